// Round 12
// baseline (3357.992 us; speedup 1.0000x reference)
//
#include <hip/hip_runtime.h>
#include <hip/hip_bf16.h>
#include <math.h>

#define TT 64
#define NN 8
#define BB 128
#define DD 128
#define HH 512
#define SS 64
#define KK 16
#define AA 16
#define NB 1024
#define H3 (3*HH)       /* 1536 */

typedef float f4v  __attribute__((ext_vector_type(4)));
typedef float f16v __attribute__((ext_vector_type(16)));
typedef short bf16x8 __attribute__((ext_vector_type(8)));

__device__ __forceinline__ float sigm(float x){ return 1.0f/(1.0f+expf(-x)); }
__device__ __forceinline__ unsigned short f2bf(float f){
  unsigned u = __float_as_uint(f);
  u += 0x7FFF + ((u >> 16) & 1);          // round-to-nearest-even
  return (unsigned short)(u >> 16);
}
__device__ __forceinline__ float bf2f(unsigned short h){
  return __uint_as_float(((unsigned)h) << 16);
}

// ---------------- done-layout detection + mask expansion ----------------
__global__ __launch_bounds__(256) void k_detect(const unsigned char* __restrict__ raw,
                                                int* __restrict__ flag)
{
  __shared__ int cA, cB;
  if (threadIdx.x == 0){ cA = 0; cB = 0; }
  __syncthreads();
  int a = 0, b = 0;
  for (int i = threadIdx.x; i < TT*NB; i += 256){
    unsigned char v = raw[i];
    if (v > 1) a++;
    if ((i & 3) != 0 && v != 0) b++;
  }
  atomicAdd(&cA, a); atomicAdd(&cB, b);
  __syncthreads();
  if (threadIdx.x == 0) *flag = (cB == 0) ? 0 : (cA == 0 ? 1 : 2);
}

__global__ __launch_bounds__(256) void k_mask(const unsigned char* __restrict__ raw,
                                              const int* __restrict__ flag,
                                              float* __restrict__ mask)
{
  int i = blockIdx.x*256 + threadIdx.x;
  if (i >= TT*NB) return;
  int f = *flag;
  int v;
  if (f == 1)      v = (int)raw[i];
  else if (f == 0) v = ((const int*)raw)[i];
  else             v = (((const float*)raw)[i] != 0.0f);
  mask[i] = v ? 0.f : 1.f;   // 0 => reset carry
}

// ---------------- small setup kernels ----------------

__global__ __launch_bounds__(256) void k_e(const float* __restrict__ W_e1, const float* __restrict__ b_e1,
                                           const float* __restrict__ W_e2, const float* __restrict__ b_e2,
                                           float* __restrict__ e_out)
{
  __shared__ float r1[KK*SS];
  int tid = threadIdx.x;
  for (int i=0;i<4;++i){ int l = tid + i*256; float v = W_e1[l] + b_e1[l & 63]; r1[l] = v > 0.f ? v : 0.f; }
  __syncthreads();
  for (int i=0;i<4;++i){
    int l = tid + i*256; int k = l >> 6, s = l & 63;
    float acc = b_e2[s];
    #pragma unroll 8
    for (int sp=0; sp<64; ++sp) acc += r1[k*64+sp] * W_e2[sp*64 + s];
    e_out[l] = tanhf(acc);
  }
}

__global__ __launch_bounds__(256) void k_w1b1(const float* __restrict__ e, const float* __restrict__ W_w1,
                                              const float* __restrict__ b_w1, const float* __restrict__ W_b1,
                                              const float* __restrict__ b_b1, float* __restrict__ w1,
                                              float* __restrict__ b1)
{
  __shared__ float es[KK*SS];
  int tid = threadIdx.x;
  for (int i=0;i<4;++i) es[tid + i*256] = e[tid + i*256];
  __syncthreads();
  for (int i=0;i<4;++i){
    int l = blockIdx.x*1024 + tid + i*256;
    int k = l >> 13, m = l & 8191;
    float acc = b_w1[m];
    #pragma unroll 8
    for (int s=0;s<64;++s) acc += es[k*64+s] * W_w1[(size_t)s*8192 + m];
    w1[l] = acc;
  }
  if (blockIdx.x == 0){
    int k = tid >> 4, a = tid & 15;
    float acc = b_b1[a];
    #pragma unroll 8
    for (int s=0;s<64;++s) acc += es[k*64+s] * W_b1[s*16 + a];
    b1[tid] = acc;
  }
}

__global__ __launch_bounds__(256) void k_se(const float* __restrict__ e, float* __restrict__ outse)
{
  __shared__ float4 es[256];
  es[threadIdx.x] = ((const float4*)e)[threadIdx.x];
  __syncthreads();
  const int total4 = TT*BB*KK*SS/4;
  for (int i = blockIdx.x*256 + threadIdx.x; i < total4; i += gridDim.x*256)
    ((float4*)outse)[i] = es[i & 255];
}

__global__ void k_copy(const float* __restrict__ src, float* __restrict__ dst, int n4)
{
  int i = blockIdx.x*blockDim.x + threadIdx.x;
  if (i < n4) ((float4*)dst)[i] = ((const float4*)src)[i];
}

// merge hi/lo bf16 pair -> f32 (8 elems/thread)
__global__ void k_merge(const unsigned short* __restrict__ h, const unsigned short* __restrict__ l,
                        float* __restrict__ o, int n8)
{
  int i = blockIdx.x*blockDim.x + threadIdx.x;
  if (i >= n8) return;
  uint4 vh = *(const uint4*)&h[(size_t)i*8];
  uint4 vl = *(const uint4*)&l[(size_t)i*8];
  const unsigned short* ph = (const unsigned short*)&vh;
  const unsigned short* pl = (const unsigned short*)&vl;
  float4 o0, o1;
  o0.x = bf2f(ph[0])+bf2f(pl[0]); o0.y = bf2f(ph[1])+bf2f(pl[1]);
  o0.z = bf2f(ph[2])+bf2f(pl[2]); o0.w = bf2f(ph[3])+bf2f(pl[3]);
  o1.x = bf2f(ph[4])+bf2f(pl[4]); o1.y = bf2f(ph[5])+bf2f(pl[5]);
  o1.z = bf2f(ph[6])+bf2f(pl[6]); o1.w = bf2f(ph[7])+bf2f(pl[7]);
  float4* d = (float4*)&o[(size_t)i*8];
  d[0] = o0; d[1] = o1;
}

// f32 -> bf16 flat cast (8 elems/thread)
__global__ void k_cast_bf16(const float* __restrict__ src, unsigned short* __restrict__ dst, int n8)
{
  int i = blockIdx.x*blockDim.x + threadIdx.x;
  if (i >= n8) return;
  const float4* s = (const float4*)(src + (size_t)i*8);
  float4 a = s[0], b = s[1];
  union { unsigned short u[8]; uint4 v; } p;
  p.u[0]=f2bf(a.x); p.u[1]=f2bf(a.y); p.u[2]=f2bf(a.z); p.u[3]=f2bf(a.w);
  p.u[4]=f2bf(b.x); p.u[5]=f2bf(b.y); p.u[6]=f2bf(b.z); p.u[7]=f2bf(b.w);
  *(uint4*)&dst[(size_t)i*8] = p.v;
}

// generic transpose + split: W [Kd][Nc] f32 -> WTh/WTl [Nc][Kd] bf16
__global__ __launch_bounds__(256) void k_tsplit(const float* __restrict__ W,
                                                unsigned short* __restrict__ WTh,
                                                unsigned short* __restrict__ WTl,
                                                int Kd, int Nc)
{
  __shared__ float t[32][33];
  int n0 = blockIdx.x * 32;
  int k0 = blockIdx.y * 32;
  int c = threadIdx.x & 31, r8 = threadIdx.x >> 5;
  for (int i=0;i<4;++i){
    int r = r8 + i*8;
    t[r][c] = W[(size_t)(k0+r)*Nc + n0 + c];
  }
  __syncthreads();
  for (int i=0;i<4;++i){
    int nr = r8 + i*8;
    float v = t[c][nr];
    unsigned short hi = f2bf(v);
    WTh[(size_t)(n0+nr)*Kd + k0 + c] = hi;
    WTl[(size_t)(n0+nr)*Kd + k0 + c] = f2bf(v - bf2f(hi));
  }
}

// f32 -> (hi, lo) bf16 flat split-cast, 8 elems/thread
__global__ void k_split_cast(const float* __restrict__ src,
                             unsigned short* __restrict__ dh,
                             unsigned short* __restrict__ dl, int n8)
{
  int i = blockIdx.x*blockDim.x + threadIdx.x;
  if (i >= n8) return;
  const float4* s = (const float4*)(src + (size_t)i*8);
  float4 a = s[0], b = s[1];
  float x[8] = {a.x,a.y,a.z,a.w,b.x,b.y,b.z,b.w};
  union { unsigned short u[8]; uint4 v; } ph, pl;
  #pragma unroll
  for (int j=0;j<8;++j){
    unsigned short hi = f2bf(x[j]);
    ph.u[j] = hi;
    pl.u[j] = f2bf(x[j] - bf2f(hi));
  }
  *(uint4*)&dh[(size_t)i*8] = ph.v;
  *(uint4*)&dl[(size_t)i*8] = pl.v;
}

// ---------------- unified MFMA GEMM (validated round 10) ----------------
template<int KD, int SPLIT, int NTILE, int RELU, int OUTMODE>
__global__ __launch_bounds__(256) void mfma_gemm(
    const unsigned short* Ah, const unsigned short* Al,
    const unsigned short* Bh, const unsigned short* Bl,
    const float* __restrict__ bias,
    float* C, unsigned short* Chi, unsigned short* Clo, int Nstride)
{
  constexpr int NFC = NTILE/16;
  __shared__ __align__(16) unsigned short AsH[128*40];
  __shared__ __align__(16) unsigned short BsH[NTILE*40];
  __shared__ __align__(16) unsigned short AsL[SPLIT ? 128*40 : 8];
  __shared__ __align__(16) unsigned short BsL[SPLIT ? NTILE*40 : 8];
  int tid = threadIdx.x;
  int w = tid >> 6, l = tid & 63;
  int lr = l & 15, lk = (l >> 4) * 8, lq = l >> 4;
  int rowBase = blockIdx.y * 128, colBase = blockIdx.x * NTILE;
  f4v acc[2][NFC];
  f4v z = {0.f,0.f,0.f,0.f};
  #pragma unroll
  for (int i=0;i<2;++i)
    #pragma unroll
    for (int j=0;j<NFC;++j) acc[i][j] = z;

  for (int k0 = 0; k0 < KD; k0 += 32){
    {
      int r = tid >> 1, half = tid & 1;
      size_t src = (size_t)(rowBase + r)*KD + k0 + half*16;
      bf16x8* dA = (bf16x8*)&AsH[r*40 + half*16];
      dA[0] = *(const bf16x8*)&Ah[src];
      dA[1] = *(const bf16x8*)&Ah[src + 8];
      if (SPLIT){
        bf16x8* dL = (bf16x8*)&AsL[r*40 + half*16];
        dL[0] = *(const bf16x8*)&Al[src];
        dL[1] = *(const bf16x8*)&Al[src + 8];
      }
    }
    if (NTILE == 128){
      int r = tid >> 1, half = tid & 1;
      size_t src = (size_t)(colBase + r)*KD + k0 + half*16;
      bf16x8* dB = (bf16x8*)&BsH[r*40 + half*16];
      dB[0] = *(const bf16x8*)&Bh[src];
      dB[1] = *(const bf16x8*)&Bh[src + 8];
      if (SPLIT){
        bf16x8* dL = (bf16x8*)&BsL[r*40 + half*16];
        dL[0] = *(const bf16x8*)&Bl[src];
        dL[1] = *(const bf16x8*)&Bl[src + 8];
      }
    } else {   // NTILE == 64
      int r = tid >> 2, q = tid & 3;
      size_t src = (size_t)(colBase + r)*KD + k0 + q*8;
      *(bf16x8*)&BsH[r*40 + q*8] = *(const bf16x8*)&Bh[src];
      if (SPLIT)
        *(bf16x8*)&BsL[r*40 + q*8] = *(const bf16x8*)&Bl[src];
    }
    __syncthreads();
    bf16x8 aH0 = *(const bf16x8*)&AsH[(w*32 + lr)*40 + lk];
    bf16x8 aH1 = *(const bf16x8*)&AsH[(w*32 + 16 + lr)*40 + lk];
    bf16x8 aL0, aL1;
    if (SPLIT){
      aL0 = *(const bf16x8*)&AsL[(w*32 + lr)*40 + lk];
      aL1 = *(const bf16x8*)&AsL[(w*32 + 16 + lr)*40 + lk];
    }
    #pragma unroll
    for (int fc=0; fc<NFC; ++fc){
      bf16x8 bH = *(const bf16x8*)&BsH[(fc*16 + lr)*40 + lk];
      acc[0][fc] = __builtin_amdgcn_mfma_f32_16x16x32_bf16(aH0, bH, acc[0][fc], 0,0,0);
      acc[1][fc] = __builtin_amdgcn_mfma_f32_16x16x32_bf16(aH1, bH, acc[1][fc], 0,0,0);
      if (SPLIT){
        bf16x8 bL = *(const bf16x8*)&BsL[(fc*16 + lr)*40 + lk];
        acc[0][fc] = __builtin_amdgcn_mfma_f32_16x16x32_bf16(aH0, bL, acc[0][fc], 0,0,0);
        acc[1][fc] = __builtin_amdgcn_mfma_f32_16x16x32_bf16(aH1, bL, acc[1][fc], 0,0,0);
        acc[0][fc] = __builtin_amdgcn_mfma_f32_16x16x32_bf16(aL0, bH, acc[0][fc], 0,0,0);
        acc[1][fc] = __builtin_amdgcn_mfma_f32_16x16x32_bf16(aL1, bH, acc[1][fc], 0,0,0);
      }
    }
    __syncthreads();
  }
  #pragma unroll
  for (int fr=0; fr<2; ++fr){
    #pragma unroll
    for (int fc=0; fc<NFC; ++fc){
      int col = colBase + fc*16 + lr;
      float bv = bias[col];
      #pragma unroll
      for (int r=0;r<4;++r){
        int row = rowBase + w*32 + fr*16 + lq*4 + r;
        float v = acc[fr][fc][r] + bv;
        if (RELU) v = v > 0.f ? v : 0.f;
        size_t o = (size_t)row*Nstride + col;
        if (OUTMODE == 0) C[o] = v;
        else if (OUTMODE == 1) Chi[o] = f2bf(v);
        else {
          unsigned short hi = f2bf(v);
          Chi[o] = hi;
          Clo[o] = f2bf(v - bf2f(hi));
        }
      }
    }
  }
}

// ---------------- per-step GRU, 32x32x16 MFMA, bf16-carried h (no stage conversion) ----------------
// 256 blocks: bid<128 GRU2 (plain bf16), else GRU1 (split hi/lo, ~fp32).
// h arrives already in bf16 form (pair for GRU1, single for GRU2, written by prior epilogue).
// Staging = 16B copy + scalar mask-select (mask in {0,1} => select == multiply, bit-identical).
__global__ __launch_bounds__(256) void gru_step_mix4(
    const unsigned short* __restrict__ hp1h, const unsigned short* __restrict__ hp1l,
    const float* __restrict__ hp2, const unsigned short* __restrict__ hp2b,
    const float* __restrict__ gi1, const float* __restrict__ gi2,
    const unsigned short* __restrict__ Wh1TH, const unsigned short* __restrict__ Wh1TL,
    const unsigned short* __restrict__ Wh2T,
    const float* __restrict__ bhn1, const float* __restrict__ bhn2,
    const float* __restrict__ mask_t,
    float* __restrict__ ho2, unsigned short* __restrict__ ho2b,
    unsigned short* __restrict__ y1h, unsigned short* __restrict__ y1l)
{
  __shared__ __align__(16) char smem[40960];
  int bid = blockIdx.x;
  int tid = threadIdx.x;
  int w = tid >> 6, l = tid & 63;
  int rf = w & 1, hc = w >> 1;
  int lc = l & 31, lh = l >> 5;
  int sr = tid >> 2, sg = tid & 3;
  f16v z16 = {0,0,0,0,0,0,0,0,0,0,0,0,0,0,0,0};
  uint4 zero4 = {0,0,0,0};

  if (bid < 128){
    // ===== GRU2: plain bf16, 32x32x16 =====
    unsigned short* As = (unsigned short*)smem;            // [64][40]
    unsigned short* Bs = (unsigned short*)smem + 64*40;    // [192][40]
    int ct = bid & 7, rt = bid >> 3;
    int rowBase = rt << 6, colBase = ct << 6;
    bool keep = mask_t[rowBase + sr] != 0.f;
    f16v acc[3] = {z16, z16, z16};

    uint4 pA;
    bf16x8 pB[3];
    {
      pA = *(const uint4*)&hp2b[(size_t)(rowBase + sr)*HH + sg*8];
      #pragma unroll
      for (int i=0;i<3;++i){
        int unit = i*256 + tid, brow = unit >> 2, q = unit & 3;
        int g = brow >> 6, c = brow & 63;
        pB[i] = *(const bf16x8*)&Wh2T[(size_t)(g*HH + colBase + c)*HH + q*8];
      }
    }
    for (int k0 = 0; k0 < HH; k0 += 32){
      __syncthreads();
      {
        *(uint4*)&As[sr*40 + sg*8] = keep ? pA : zero4;
        #pragma unroll
        for (int i=0;i<3;++i){
          int unit = i*256 + tid, brow = unit >> 2, q = unit & 3;
          *(bf16x8*)&Bs[brow*40 + q*8] = pB[i];
        }
      }
      __syncthreads();
      if (k0 + 32 < HH){
        pA = *(const uint4*)&hp2b[(size_t)(rowBase + sr)*HH + k0 + 32 + sg*8];
        #pragma unroll
        for (int i=0;i<3;++i){
          int unit = i*256 + tid, brow = unit >> 2, q = unit & 3;
          int g = brow >> 6, c = brow & 63;
          pB[i] = *(const bf16x8*)&Wh2T[(size_t)(g*HH + colBase + c)*HH + k0 + 32 + q*8];
        }
      }
      #pragma unroll
      for (int kc=0;kc<32;kc+=16){
        bf16x8 a = *(const bf16x8*)&As[(rf*32 + lc)*40 + kc + lh*8];
        #pragma unroll
        for (int g=0; g<3; ++g){
          bf16x8 b = *(const bf16x8*)&Bs[(g*64 + hc*32 + lc)*40 + kc + lh*8];
          acc[g] = __builtin_amdgcn_mfma_f32_32x32x16_bf16(a, b, acc[g], 0,0,0);
        }
      }
    }
    int col = colBase + hc*32 + lc;
    float bn = bhn2[col];
    #pragma unroll
    for (int r=0;r<16;++r){
      int row = rowBase + rf*32 + (r&3) + 8*(r>>2) + 4*lh;
      size_t gb = (size_t)row*H3 + col;
      float g_r = __builtin_nontemporal_load(&gi2[gb]);
      float g_z = __builtin_nontemporal_load(&gi2[gb + HH]);
      float g_n = __builtin_nontemporal_load(&gi2[gb + 2*HH]);
      float hv  = hp2[(size_t)row*HH + col] * mask_t[row];   // exact (branch-2 margin)
      float rg = sigm(g_r + acc[0][r]);
      float zg = sigm(g_z + acc[1][r]);
      float ng = tanhf(g_n + rg*(acc[2][r] + bn));
      float o  = (1.f - zg)*ng + zg*hv;
      size_t oo = (size_t)row*HH + col;
      ho2[oo] = o;
      __builtin_nontemporal_store(f2bf(o), &ho2b[oo]);       // next-step staging copy
    }
  } else {
    // ===== GRU1: split hi/lo, 32x32x16, ~fp32 precision =====
    unsigned short* AsH = (unsigned short*)smem;             // [64][40]
    unsigned short* AsL = AsH + 64*40;
    unsigned short* BsH = AsL + 64*40;                       // [192][40]
    unsigned short* BsL = BsH + 192*40;
    int bidp = bid - 128;
    int ct = bidp & 7, rt = bidp >> 3;
    int rowBase = rt << 6, colBase = ct << 6;
    int capk = colBase + hc*32;
    bool keep = mask_t[rowBase + sr] != 0.f;
    f16v acc[3] = {z16, z16, z16};
    float hval[16];

    uint4 pAh, pAl;
    bf16x8 pBH[3], pBL[3];
    {
      size_t sA = (size_t)(rowBase + sr)*HH + sg*8;
      pAh = *(const uint4*)&hp1h[sA];
      pAl = *(const uint4*)&hp1l[sA];
      #pragma unroll
      for (int i=0;i<3;++i){
        int unit = i*256 + tid, brow = unit >> 2, q = unit & 3;
        int g = brow >> 6, c = brow & 63;
        size_t src = (size_t)(g*HH + colBase + c)*HH + q*8;
        pBH[i] = *(const bf16x8*)&Wh1TH[src];
        pBL[i] = *(const bf16x8*)&Wh1TL[src];
      }
    }
    for (int k0 = 0; k0 < HH; k0 += 32){
      __syncthreads();
      {
        *(uint4*)&AsH[sr*40 + sg*8] = keep ? pAh : zero4;
        *(uint4*)&AsL[sr*40 + sg*8] = keep ? pAl : zero4;
        #pragma unroll
        for (int i=0;i<3;++i){
          int unit = i*256 + tid, brow = unit >> 2, q = unit & 3;
          *(bf16x8*)&BsH[brow*40 + q*8] = pBH[i];
          *(bf16x8*)&BsL[brow*40 + q*8] = pBL[i];
        }
      }
      __syncthreads();
      if (k0 + 32 < HH){
        size_t sA = (size_t)(rowBase + sr)*HH + k0 + 32 + sg*8;
        pAh = *(const uint4*)&hp1h[sA];
        pAl = *(const uint4*)&hp1l[sA];
        #pragma unroll
        for (int i=0;i<3;++i){
          int unit = i*256 + tid, brow = unit >> 2, q = unit & 3;
          int g = brow >> 6, c = brow & 63;
          size_t src = (size_t)(g*HH + colBase + c)*HH + k0 + 32 + q*8;
          pBH[i] = *(const bf16x8*)&Wh1TH[src];
          pBL[i] = *(const bf16x8*)&Wh1TL[src];
        }
      }
      if (k0 == capk){                 // masked h_prev at own columns (hi+lo, err ~2^-17)
        #pragma unroll
        for (int r=0;r<16;++r){
          int rl = rf*32 + (r&3) + 8*(r>>2) + 4*lh;
          hval[r] = bf2f(AsH[rl*40 + lc]) + bf2f(AsL[rl*40 + lc]);
        }
      }
      #pragma unroll
      for (int kc=0;kc<32;kc+=16){
        bf16x8 aH = *(const bf16x8*)&AsH[(rf*32 + lc)*40 + kc + lh*8];
        bf16x8 aL = *(const bf16x8*)&AsL[(rf*32 + lc)*40 + kc + lh*8];
        #pragma unroll
        for (int g=0; g<3; ++g){
          int brow = (g*64 + hc*32 + lc)*40 + kc + lh*8;
          bf16x8 bH = *(const bf16x8*)&BsH[brow];
          bf16x8 bL = *(const bf16x8*)&BsL[brow];
          acc[g] = __builtin_amdgcn_mfma_f32_32x32x16_bf16(aH, bH, acc[g], 0,0,0);
          acc[g] = __builtin_amdgcn_mfma_f32_32x32x16_bf16(aH, bL, acc[g], 0,0,0);
          acc[g] = __builtin_amdgcn_mfma_f32_32x32x16_bf16(aL, bH, acc[g], 0,0,0);
        }
      }
    }
    int col = colBase + hc*32 + lc;
    float bn = bhn1[col];
    #pragma unroll
    for (int r=0;r<16;++r){
      int row = rowBase + rf*32 + (r&3) + 8*(r>>2) + 4*lh;
      size_t gb = (size_t)row*H3 + col;
      float g_r = __builtin_nontemporal_load(&gi1[gb]);
      float g_z = __builtin_nontemporal_load(&gi1[gb + HH]);
      float g_n = __builtin_nontemporal_load(&gi1[gb + 2*HH]);
      float rg = sigm(g_r + acc[0][r]);
      float zg = sigm(g_z + acc[1][r]);
      float ng = tanhf(g_n + rg*(acc[2][r] + bn));
      float o  = (1.f - zg)*ng + zg*hval[r];
      size_t oo = (size_t)row*HH + col;
      unsigned short hi = f2bf(o);                 // y1 split store = h carry + ae2 input
      __builtin_nontemporal_store(hi, &y1h[oo]);
      __builtin_nontemporal_store(f2bf(o - bf2f(hi)), &y1l[oo]);
    }
  }
}

// ---------------- logits + first-max argmax (fully unrolled: no scratch spill) ----------------
__global__ __launch_bounds__(256) void k_logits(const float* __restrict__ ae2,
    const float* __restrict__ e, float* __restrict__ out_logits, int* __restrict__ argk, int t0)
{
  __shared__ float es[KK*SS];
  int tid = threadIdx.x;
  for (int i=0;i<4;++i) es[tid + i*256] = e[tid + i*256];
  __syncthreads();
  int g = blockIdx.x*256 + tid;
  int t = t0 + (g >> 10), j = g & 1023;
  const float* arow = &ae2[(size_t)g * SS];
  float a[SS];
  #pragma unroll
  for (int i=0;i<16;++i){ float4 v = ((const float4*)arow)[i]; a[4*i]=v.x; a[4*i+1]=v.y; a[4*i+2]=v.z; a[4*i+3]=v.w; }
  float lg[KK];
  float best = -INFINITY; int bk = 0;
  #pragma unroll
  for (int k=0;k<KK;++k){
    float s2 = 0.f;
    #pragma unroll
    for (int s=0;s<SS;++s) s2 += a[s]*es[k*SS+s];
    lg[k] = s2;
    if (s2 > best){ best = s2; bk = k; }
  }
  int n = j >> 7, b = j & 127;
  size_t ob = ((size_t)((t*BB + b)*NN + n)) * KK;
  #pragma unroll
  for (int k4=0;k4<4;++k4)
    *(float4*)&out_logits[ob + k4*4] = make_float4(lg[k4*4],lg[k4*4+1],lg[k4*4+2],lg[k4*4+3]);
  argk[(t*BB + b)*NN + n] = bk;   // (b,n)-major: matches reference's prob/q index quirk
}

// ---------------- q selection (chunked) ----------------
__global__ __launch_bounds__(64) void k_qsel(const float* __restrict__ y2,
    const float* __restrict__ w1, const float* __restrict__ b1,
    const int* __restrict__ argk, float* __restrict__ outq)
{
  __shared__ float yr[HH];
  __shared__ float part[64];
  int bj = blockIdx.x;
  int tid = threadIdx.x;
  const float4* row4 = (const float4*)&y2[(size_t)bj*HH];
  ((float4*)yr)[tid]    = row4[tid];
  ((float4*)yr)[tid+64] = row4[tid+64];
  __syncthreads();
  int k = argk[bj];
  int a = tid & 15, q4 = tid >> 4;
  const float* wp = &w1[(size_t)k*HH*AA + a];
  float s = 0.f;
  int h0 = q4*128;
  #pragma unroll 8
  for (int h=h0; h<h0+128; ++h) s += yr[h]*wp[(size_t)h*AA];
  part[tid] = s;
  __syncthreads();
  if (q4 == 0){
    float v = part[a] + part[a+16] + part[a+32] + part[a+48] + b1[k*AA + a];
    outq[(size_t)bj*AA + a] = v;
  }
}

// ---------------- orchestration ----------------
extern "C" void kernel_launch(void* const* d_in, const int* in_sizes, int n_in,
                              void* d_out, int out_size, void* d_ws, size_t ws_size,
                              hipStream_t stream)
{
  (void)in_sizes; (void)n_in; (void)out_size;
  const float* h1     = (const float*)d_in[0];
  const float* h2     = (const float*)d_in[1];
  const float* obs    = (const float*)d_in[2];
  const unsigned char* done_raw = (const unsigned char*)d_in[3];
  const float* W_embed=(const float*)d_in[4];  const float* b_embed=(const float*)d_in[5];
  const float* Wi1    =(const float*)d_in[6];  const float* bi1    =(const float*)d_in[7];
  const float* Wh1    =(const float*)d_in[8];  const float* bhn1   =(const float*)d_in[9];
  const float* W_sub  =(const float*)d_in[10]; const float* b_sub  =(const float*)d_in[11];
  const float* W_e1   =(const float*)d_in[12]; const float* b_e1   =(const float*)d_in[13];
  const float* W_e2   =(const float*)d_in[14]; const float* b_e2   =(const float*)d_in[15];
  const float* W_pol  =(const float*)d_in[16]; const float* b_pol  =(const float*)d_in[17];
  const float* Wi2    =(const float*)d_in[18]; const float* bi2    =(const float*)d_in[19];
  const float* Wh2    =(const float*)d_in[20]; const float* bhn2   =(const float*)d_in[21];
  const float* W_w1   =(const float*)d_in[22]; const float* b_w1   =(const float*)d_in[23];
  const float* W_b1   =(const float*)d_in[24]; const float* b_b1   =(const float*)d_in[25];

  float* out    = (float*)d_out;
  float* outHT1 = out;
  float* outHT2 = out + (size_t)NB*HH;
  float* outQ   = out + 2ull*NB*HH;
  float* outLG  = outQ + (size_t)TT*NB*AA;
  float* outSE  = outLG + (size_t)TT*BB*NN*KK;

  // ---- adaptive chunk size (float units) ----
  const size_t fixed_f = (size_t)TT*NB /*mask*/ + 1024 /*e*/
                       + (size_t)KK*HH*AA + 256 + (size_t)TT*NB /*argk*/ + 64
                       + 2ull*NB*HH/2      /*hl1 pair (us)*/
                       + 2ull*NB*HH/2      /*y2b 2 slots (us)*/
                       + 2ull*DD*HH/2 * 2  /*wembT, wpolT pairs*/
                       + 4ull*H3*HH        /*wi1T,wi2T,wh1T,wh2T pairs*/
                       + (size_t)HH*SS;    /*wsubT pair*/
  const size_t per_t_f = (size_t)NB*(HH + 2*H3 + SS)        // buf2, gbuf1, gbuf2, ae2buf
                       + (size_t)NB*(HH/2 + DD + HH);       // buf2bf, obs pair, y1 pair
  int CH = 64;
  while (CH > 1 && (fixed_f + per_t_f*(size_t)CH)*4 > ws_size) CH >>= 1;

  float* buf2   = (float*)d_ws;                        // y2 chunk (f32): CH*NB*HH
  float* gbuf1  = buf2   + (size_t)CH*NB*HH;           // gi1 chunk
  float* gbuf2  = gbuf1  + (size_t)CH*NB*H3;           // gi2 chunk
  float* ae2buf = gbuf2  + (size_t)CH*NB*H3;           // CH*NB*SS
  float* maskp  = ae2buf + (size_t)CH*NB*SS;
  float* ws_e   = maskp  + (size_t)TT*NB;
  float* ws_w1  = ws_e   + 1024;
  float* ws_b1  = ws_w1  + (size_t)KK*HH*AA;
  int*   ws_argk= (int*)(ws_b1 + 256);
  int*   ws_flag= (int*)(ws_argk + (size_t)TT*NB);
  unsigned short* buf2bf = (unsigned short*)(ws_flag + 64);   // CH*NB*HH (sp bf16)
  unsigned short* obs_h  = buf2bf + (size_t)CH*NB*HH;         // CH*NB*DD
  unsigned short* obs_l  = obs_h  + (size_t)CH*NB*DD;
  unsigned short* y1_h   = obs_l  + (size_t)CH*NB*DD;         // CH*NB*HH (y1 pair = h1 carry)
  unsigned short* y1_l   = y1_h   + (size_t)CH*NB*HH;
  unsigned short* hl1h   = y1_l   + (size_t)CH*NB*HH;         // NB*HH chunk-carry pair
  unsigned short* hl1l   = hl1h   + (size_t)NB*HH;
  unsigned short* y2b0   = hl1l   + (size_t)NB*HH;            // GRU2 bf16 h, 2 slots
  unsigned short* y2b1   = y2b0   + (size_t)NB*HH;
  unsigned short* wembt_h= y2b1   + (size_t)NB*HH;
  unsigned short* wembt_l= wembt_h+ (size_t)HH*DD;
  unsigned short* wpolt_h= wembt_l+ (size_t)HH*DD;
  unsigned short* wpolt_l= wpolt_h+ (size_t)HH*DD;
  unsigned short* wi1t_h = wpolt_l+ (size_t)HH*DD;
  unsigned short* wi1t_l = wi1t_h + (size_t)H3*HH;
  unsigned short* wi2t_h = wi1t_l + (size_t)H3*HH;
  unsigned short* wi2t_l = wi2t_h + (size_t)H3*HH;
  unsigned short* wh1t_h = wi2t_l + (size_t)H3*HH;
  unsigned short* wh1t_l = wh1t_h + (size_t)H3*HH;
  unsigned short* wh2t_h = wh1t_l + (size_t)H3*HH;
  unsigned short* wh2t_l = wh2t_h + (size_t)H3*HH;
  unsigned short* wsubt_h= wh2t_l + (size_t)H3*HH;
  unsigned short* wsubt_l= wsubt_h+ (size_t)SS*HH;
  unsigned short* y2bslot[2] = { y2b0, y2b1 };

  // phase 0
  k_detect<<<1,256,0,stream>>>(done_raw, ws_flag);
  k_mask<<<TT*NB/256,256,0,stream>>>(done_raw, ws_flag, maskp);
  k_e<<<1,256,0,stream>>>(W_e1,b_e1,W_e2,b_e2,ws_e);
  k_w1b1<<<128,256,0,stream>>>(ws_e,W_w1,b_w1,W_b1,b_b1,ws_w1,ws_b1);
  k_se<<<2048,256,0,stream>>>(ws_e,outSE);
  k_tsplit<<<dim3(16,4),256,0,stream>>>(W_embed, wembt_h, wembt_l, DD, HH);
  k_tsplit<<<dim3(16,4),256,0,stream>>>(W_pol,   wpolt_h, wpolt_l, DD, HH);
  k_tsplit<<<dim3(48,16),256,0,stream>>>(Wi1, wi1t_h, wi1t_l, HH, H3);
  k_tsplit<<<dim3(48,16),256,0,stream>>>(Wi2, wi2t_h, wi2t_l, HH, H3);
  k_tsplit<<<dim3(48,16),256,0,stream>>>(Wh1, wh1t_h, wh1t_l, HH, H3);
  k_tsplit<<<dim3(48,16),256,0,stream>>>(Wh2, wh2t_h, wh2t_l, HH, H3);
  k_tsplit<<<dim3(2,16),256,0,stream>>>(W_sub, wsubt_h, wsubt_l, HH, SS);
  k_split_cast<<<NB*HH/8/256,256,0,stream>>>(h1, hl1h, hl1l, NB*HH/8);   // GRU1 carry pair
  k_cast_bf16<<<NB*HH/8/256,256,0,stream>>>(h2, y2b1, NB*HH/8);          // GRU2 carry (gstep=0 reads slot 1)

  dim3 thr(256);
  const int NCH = TT / CH;
  for (int c = 0; c < NCH; ++c){
    int t0 = c * CH;
    int M = CH*NB;
    const float* obs_c = obs + (size_t)t0*NB*DD;
    k_split_cast<<<(M*DD/8+255)/256,256,0,stream>>>(obs_c, obs_h, obs_l, M*DD/8);
    mfma_gemm<DD,1,128,1,2><<<dim3(HH/128, M/128),thr,0,stream>>>(
        obs_h, obs_l, wembt_h, wembt_l, b_embed, nullptr, y1_h, y1_l, HH);   // ae pair staged into y1 slots temp? no: separate below
    // NOTE: ae pair must not alias y1; reuse obs staging trick is unsafe. Use dedicated region:
    // (ae pair occupies buf2bf? buf2bf needed for sp.) -> compute gi1 immediately from the pair
    mfma_gemm<HH,1,128,0,0><<<dim3(H3/128, M/128),thr,0,stream>>>(
        y1_h, y1_l, wi1t_h, wi1t_l, bi1, gbuf1, nullptr, nullptr, H3);
    mfma_gemm<DD,0,128,1,1><<<dim3(HH/128, M/128),thr,0,stream>>>(
        obs_h, obs_h, wpolt_h, wpolt_h, b_pol, nullptr, buf2bf, nullptr, HH);
    mfma_gemm<HH,0,128,0,0><<<dim3(H3/128, M/128),thr,0,stream>>>(
        buf2bf, buf2bf, wi2t_h, wi2t_h, bi2, gbuf2, nullptr, nullptr, H3);
    // dual-GRU scan: h carried as bf16 (pair for GRU1, single for GRU2)
    for (int lt = 0; lt < CH; ++lt){
      int gstep = t0 + lt;
      const unsigned short* hp1h = (lt == 0) ? hl1h : (y1_h + (size_t)(lt-1)*NB*HH);
      const unsigned short* hp1l = (lt == 0) ? hl1l : (y1_l + (size_t)(lt-1)*NB*HH);
      const float* hp2 = (c == 0 && lt == 0) ? h2 :
                         (lt == 0 ? buf2 + (size_t)(CH-1)*NB*HH : buf2 + (size_t)(lt-1)*NB*HH);
      const unsigned short* hp2b = y2bslot[(gstep+1)&1];
      gru_step_mix4<<<256, 256, 0, stream>>>(hp1h, hp1l, hp2, hp2b,
                                             gbuf1 + (size_t)lt*NB*H3, gbuf2 + (size_t)lt*NB*H3,
                                             wh1t_h, wh1t_l, wh2t_h, bhn1, bhn2,
                                             maskp + (size_t)gstep*NB,
                                             buf2 + (size_t)lt*NB*HH, y2bslot[gstep&1],
                                             y1_h + (size_t)lt*NB*HH, y1_l + (size_t)lt*NB*HH);
    }
    // chunk carry for GRU1 (copy last y1 pair slot; ushort n4 counted in float4 units)
    k_copy<<<256,256,0,stream>>>((const float*)(y1_h + (size_t)(CH-1)*NB*HH), (float*)hl1h, NB*HH/8);
    k_copy<<<256,256,0,stream>>>((const float*)(y1_l + (size_t)(CH-1)*NB*HH), (float*)hl1l, NB*HH/8);
    // tails: ae2 via split MFMA (y1 pair produced by scan), logits, qsel
    mfma_gemm<HH,1,64,0,0><<<dim3(1, M/128),thr,0,stream>>>(
        y1_h, y1_l, wsubt_h, wsubt_l, b_sub, ae2buf, nullptr, nullptr, SS);
    k_logits<<<M/256,256,0,stream>>>(ae2buf, ws_e, outLG, ws_argk, t0);
    k_qsel<<<M,64,0,stream>>>(buf2, ws_w1, ws_b1, ws_argk + (size_t)t0*NB, outQ + (size_t)t0*NB*AA);
  }
  k_merge<<<NB*HH/8/256,256,0,stream>>>(hl1h, hl1l, outHT1, NB*HH/8);
  k_copy<<<512,256,0,stream>>>(buf2 + (size_t)(CH-1)*NB*HH, outHT2, NB*HH/4);
}

// Round 13
// 3302.829 us; speedup vs baseline: 1.0167x; 1.0167x over previous
//
#include <hip/hip_runtime.h>
#include <hip/hip_bf16.h>
#include <math.h>

#define TT 64
#define NN 8
#define BB 128
#define DD 128
#define HH 512
#define SS 64
#define KK 16
#define AA 16
#define NB 1024
#define H3 (3*HH)       /* 1536 */

typedef float f4v  __attribute__((ext_vector_type(4)));
typedef float f16v __attribute__((ext_vector_type(16)));
typedef short bf16x8 __attribute__((ext_vector_type(8)));

__device__ __forceinline__ float sigm(float x){ return 1.0f/(1.0f+expf(-x)); }
__device__ __forceinline__ unsigned short f2bf(float f){
  unsigned u = __float_as_uint(f);
  u += 0x7FFF + ((u >> 16) & 1);          // round-to-nearest-even
  return (unsigned short)(u >> 16);
}
__device__ __forceinline__ float bf2f(unsigned short h){
  return __uint_as_float(((unsigned)h) << 16);
}

// ---------------- done-layout detection + mask expansion ----------------
__global__ __launch_bounds__(256) void k_detect(const unsigned char* __restrict__ raw,
                                                int* __restrict__ flag)
{
  __shared__ int cA, cB;
  if (threadIdx.x == 0){ cA = 0; cB = 0; }
  __syncthreads();
  int a = 0, b = 0;
  for (int i = threadIdx.x; i < TT*NB; i += 256){
    unsigned char v = raw[i];
    if (v > 1) a++;
    if ((i & 3) != 0 && v != 0) b++;
  }
  atomicAdd(&cA, a); atomicAdd(&cB, b);
  __syncthreads();
  if (threadIdx.x == 0) *flag = (cB == 0) ? 0 : (cA == 0 ? 1 : 2);
}

__global__ __launch_bounds__(256) void k_mask(const unsigned char* __restrict__ raw,
                                              const int* __restrict__ flag,
                                              float* __restrict__ mask)
{
  int i = blockIdx.x*256 + threadIdx.x;
  if (i >= TT*NB) return;
  int f = *flag;
  int v;
  if (f == 1)      v = (int)raw[i];
  else if (f == 0) v = ((const int*)raw)[i];
  else             v = (((const float*)raw)[i] != 0.0f);
  mask[i] = v ? 0.f : 1.f;   // 0 => reset carry
}

// ---------------- small setup kernels ----------------

__global__ __launch_bounds__(256) void k_e(const float* __restrict__ W_e1, const float* __restrict__ b_e1,
                                           const float* __restrict__ W_e2, const float* __restrict__ b_e2,
                                           float* __restrict__ e_out)
{
  __shared__ float r1[KK*SS];
  int tid = threadIdx.x;
  for (int i=0;i<4;++i){ int l = tid + i*256; float v = W_e1[l] + b_e1[l & 63]; r1[l] = v > 0.f ? v : 0.f; }
  __syncthreads();
  for (int i=0;i<4;++i){
    int l = tid + i*256; int k = l >> 6, s = l & 63;
    float acc = b_e2[s];
    #pragma unroll 8
    for (int sp=0; sp<64; ++sp) acc += r1[k*64+sp] * W_e2[sp*64 + s];
    e_out[l] = tanhf(acc);
  }
}

__global__ __launch_bounds__(256) void k_w1b1(const float* __restrict__ e, const float* __restrict__ W_w1,
                                              const float* __restrict__ b_w1, const float* __restrict__ W_b1,
                                              const float* __restrict__ b_b1, float* __restrict__ w1,
                                              float* __restrict__ b1)
{
  __shared__ float es[KK*SS];
  int tid = threadIdx.x;
  for (int i=0;i<4;++i) es[tid + i*256] = e[tid + i*256];
  __syncthreads();
  for (int i=0;i<4;++i){
    int l = blockIdx.x*1024 + tid + i*256;
    int k = l >> 13, m = l & 8191;
    float acc = b_w1[m];
    #pragma unroll 8
    for (int s=0;s<64;++s) acc += es[k*64+s] * W_w1[(size_t)s*8192 + m];
    w1[l] = acc;
  }
  if (blockIdx.x == 0){
    int k = tid >> 4, a = tid & 15;
    float acc = b_b1[a];
    #pragma unroll 8
    for (int s=0;s<64;++s) acc += es[k*64+s] * W_b1[s*16 + a];
    b1[tid] = acc;
  }
}

__global__ __launch_bounds__(256) void k_se(const float* __restrict__ e, float* __restrict__ outse)
{
  __shared__ float4 es[256];
  es[threadIdx.x] = ((const float4*)e)[threadIdx.x];
  __syncthreads();
  const int total4 = TT*BB*KK*SS/4;
  for (int i = blockIdx.x*256 + threadIdx.x; i < total4; i += gridDim.x*256)
    ((float4*)outse)[i] = es[i & 255];
}

__global__ void k_copy(const float* __restrict__ src, float* __restrict__ dst, int n4)
{
  int i = blockIdx.x*blockDim.x + threadIdx.x;
  if (i < n4) ((float4*)dst)[i] = ((const float4*)src)[i];
}

// merge hi/lo bf16 pair -> f32 (8 elems/thread)
__global__ void k_merge(const unsigned short* __restrict__ h, const unsigned short* __restrict__ l,
                        float* __restrict__ o, int n8)
{
  int i = blockIdx.x*blockDim.x + threadIdx.x;
  if (i >= n8) return;
  uint4 vh = *(const uint4*)&h[(size_t)i*8];
  uint4 vl = *(const uint4*)&l[(size_t)i*8];
  const unsigned short* ph = (const unsigned short*)&vh;
  const unsigned short* pl = (const unsigned short*)&vl;
  float4 o0, o1;
  o0.x = bf2f(ph[0])+bf2f(pl[0]); o0.y = bf2f(ph[1])+bf2f(pl[1]);
  o0.z = bf2f(ph[2])+bf2f(pl[2]); o0.w = bf2f(ph[3])+bf2f(pl[3]);
  o1.x = bf2f(ph[4])+bf2f(pl[4]); o1.y = bf2f(ph[5])+bf2f(pl[5]);
  o1.z = bf2f(ph[6])+bf2f(pl[6]); o1.w = bf2f(ph[7])+bf2f(pl[7]);
  float4* d = (float4*)&o[(size_t)i*8];
  d[0] = o0; d[1] = o1;
}

// f32 -> bf16 flat cast (8 elems/thread)
__global__ void k_cast_bf16(const float* __restrict__ src, unsigned short* __restrict__ dst, int n8)
{
  int i = blockIdx.x*blockDim.x + threadIdx.x;
  if (i >= n8) return;
  const float4* s = (const float4*)(src + (size_t)i*8);
  float4 a = s[0], b = s[1];
  union { unsigned short u[8]; uint4 v; } p;
  p.u[0]=f2bf(a.x); p.u[1]=f2bf(a.y); p.u[2]=f2bf(a.z); p.u[3]=f2bf(a.w);
  p.u[4]=f2bf(b.x); p.u[5]=f2bf(b.y); p.u[6]=f2bf(b.z); p.u[7]=f2bf(b.w);
  *(uint4*)&dst[(size_t)i*8] = p.v;
}

// generic transpose + split: W [Kd][Nc] f32 -> WTh/WTl [Nc][Kd] bf16
__global__ __launch_bounds__(256) void k_tsplit(const float* __restrict__ W,
                                                unsigned short* __restrict__ WTh,
                                                unsigned short* __restrict__ WTl,
                                                int Kd, int Nc)
{
  __shared__ float t[32][33];
  int n0 = blockIdx.x * 32;
  int k0 = blockIdx.y * 32;
  int c = threadIdx.x & 31, r8 = threadIdx.x >> 5;
  for (int i=0;i<4;++i){
    int r = r8 + i*8;
    t[r][c] = W[(size_t)(k0+r)*Nc + n0 + c];
  }
  __syncthreads();
  for (int i=0;i<4;++i){
    int nr = r8 + i*8;
    float v = t[c][nr];
    unsigned short hi = f2bf(v);
    WTh[(size_t)(n0+nr)*Kd + k0 + c] = hi;
    WTl[(size_t)(n0+nr)*Kd + k0 + c] = f2bf(v - bf2f(hi));
  }
}

// f32 -> (hi, lo) bf16 flat split-cast, 8 elems/thread
__global__ void k_split_cast(const float* __restrict__ src,
                             unsigned short* __restrict__ dh,
                             unsigned short* __restrict__ dl, int n8)
{
  int i = blockIdx.x*blockDim.x + threadIdx.x;
  if (i >= n8) return;
  const float4* s = (const float4*)(src + (size_t)i*8);
  float4 a = s[0], b = s[1];
  float x[8] = {a.x,a.y,a.z,a.w,b.x,b.y,b.z,b.w};
  union { unsigned short u[8]; uint4 v; } ph, pl;
  #pragma unroll
  for (int j=0;j<8;++j){
    unsigned short hi = f2bf(x[j]);
    ph.u[j] = hi;
    pl.u[j] = f2bf(x[j] - bf2f(hi));
  }
  *(uint4*)&dh[(size_t)i*8] = ph.v;
  *(uint4*)&dl[(size_t)i*8] = pl.v;
}

// ---------------- unified MFMA GEMM (validated round 10) ----------------
template<int KD, int SPLIT, int NTILE, int RELU, int OUTMODE>
__global__ __launch_bounds__(256) void mfma_gemm(
    const unsigned short* Ah, const unsigned short* Al,
    const unsigned short* Bh, const unsigned short* Bl,
    const float* __restrict__ bias,
    float* C, unsigned short* Chi, unsigned short* Clo, int Nstride)
{
  constexpr int NFC = NTILE/16;
  __shared__ __align__(16) unsigned short AsH[128*40];
  __shared__ __align__(16) unsigned short BsH[NTILE*40];
  __shared__ __align__(16) unsigned short AsL[SPLIT ? 128*40 : 8];
  __shared__ __align__(16) unsigned short BsL[SPLIT ? NTILE*40 : 8];
  int tid = threadIdx.x;
  int w = tid >> 6, l = tid & 63;
  int lr = l & 15, lk = (l >> 4) * 8, lq = l >> 4;
  int rowBase = blockIdx.y * 128, colBase = blockIdx.x * NTILE;
  f4v acc[2][NFC];
  f4v z = {0.f,0.f,0.f,0.f};
  #pragma unroll
  for (int i=0;i<2;++i)
    #pragma unroll
    for (int j=0;j<NFC;++j) acc[i][j] = z;

  for (int k0 = 0; k0 < KD; k0 += 32){
    {
      int r = tid >> 1, half = tid & 1;
      size_t src = (size_t)(rowBase + r)*KD + k0 + half*16;
      bf16x8* dA = (bf16x8*)&AsH[r*40 + half*16];
      dA[0] = *(const bf16x8*)&Ah[src];
      dA[1] = *(const bf16x8*)&Ah[src + 8];
      if (SPLIT){
        bf16x8* dL = (bf16x8*)&AsL[r*40 + half*16];
        dL[0] = *(const bf16x8*)&Al[src];
        dL[1] = *(const bf16x8*)&Al[src + 8];
      }
    }
    if (NTILE == 128){
      int r = tid >> 1, half = tid & 1;
      size_t src = (size_t)(colBase + r)*KD + k0 + half*16;
      bf16x8* dB = (bf16x8*)&BsH[r*40 + half*16];
      dB[0] = *(const bf16x8*)&Bh[src];
      dB[1] = *(const bf16x8*)&Bh[src + 8];
      if (SPLIT){
        bf16x8* dL = (bf16x8*)&BsL[r*40 + half*16];
        dL[0] = *(const bf16x8*)&Bl[src];
        dL[1] = *(const bf16x8*)&Bl[src + 8];
      }
    } else {   // NTILE == 64
      int r = tid >> 2, q = tid & 3;
      size_t src = (size_t)(colBase + r)*KD + k0 + q*8;
      *(bf16x8*)&BsH[r*40 + q*8] = *(const bf16x8*)&Bh[src];
      if (SPLIT)
        *(bf16x8*)&BsL[r*40 + q*8] = *(const bf16x8*)&Bl[src];
    }
    __syncthreads();
    bf16x8 aH0 = *(const bf16x8*)&AsH[(w*32 + lr)*40 + lk];
    bf16x8 aH1 = *(const bf16x8*)&AsH[(w*32 + 16 + lr)*40 + lk];
    bf16x8 aL0, aL1;
    if (SPLIT){
      aL0 = *(const bf16x8*)&AsL[(w*32 + lr)*40 + lk];
      aL1 = *(const bf16x8*)&AsL[(w*32 + 16 + lr)*40 + lk];
    }
    #pragma unroll
    for (int fc=0; fc<NFC; ++fc){
      bf16x8 bH = *(const bf16x8*)&BsH[(fc*16 + lr)*40 + lk];
      acc[0][fc] = __builtin_amdgcn_mfma_f32_16x16x32_bf16(aH0, bH, acc[0][fc], 0,0,0);
      acc[1][fc] = __builtin_amdgcn_mfma_f32_16x16x32_bf16(aH1, bH, acc[1][fc], 0,0,0);
      if (SPLIT){
        bf16x8 bL = *(const bf16x8*)&BsL[(fc*16 + lr)*40 + lk];
        acc[0][fc] = __builtin_amdgcn_mfma_f32_16x16x32_bf16(aH0, bL, acc[0][fc], 0,0,0);
        acc[1][fc] = __builtin_amdgcn_mfma_f32_16x16x32_bf16(aH1, bL, acc[1][fc], 0,0,0);
        acc[0][fc] = __builtin_amdgcn_mfma_f32_16x16x32_bf16(aL0, bH, acc[0][fc], 0,0,0);
        acc[1][fc] = __builtin_amdgcn_mfma_f32_16x16x32_bf16(aL1, bH, acc[1][fc], 0,0,0);
      }
    }
    __syncthreads();
  }
  #pragma unroll
  for (int fr=0; fr<2; ++fr){
    #pragma unroll
    for (int fc=0; fc<NFC; ++fc){
      int col = colBase + fc*16 + lr;
      float bv = bias[col];
      #pragma unroll
      for (int r=0;r<4;++r){
        int row = rowBase + w*32 + fr*16 + lq*4 + r;
        float v = acc[fr][fc][r] + bv;
        if (RELU) v = v > 0.f ? v : 0.f;
        size_t o = (size_t)row*Nstride + col;
        if (OUTMODE == 0) C[o] = v;
        else if (OUTMODE == 1) Chi[o] = f2bf(v);
        else {
          unsigned short hi = f2bf(v);
          Chi[o] = hi;
          Clo[o] = f2bf(v - bf2f(hi));
        }
      }
    }
  }
}

// ---------------- per-step GRU, 32x32x16 MFMA, bf16-carried h (cached carry stores) ----------------
__global__ __launch_bounds__(256) void gru_step_mix4(
    const unsigned short* __restrict__ hp1h, const unsigned short* __restrict__ hp1l,
    const float* __restrict__ hp2, const unsigned short* __restrict__ hp2b,
    const float* __restrict__ gi1, const float* __restrict__ gi2,
    const unsigned short* __restrict__ Wh1TH, const unsigned short* __restrict__ Wh1TL,
    const unsigned short* __restrict__ Wh2T,
    const float* __restrict__ bhn1, const float* __restrict__ bhn2,
    const float* __restrict__ mask_t,
    float* __restrict__ ho2, unsigned short* __restrict__ ho2b,
    unsigned short* __restrict__ y1h, unsigned short* __restrict__ y1l)
{
  __shared__ __align__(16) char smem[40960];
  int bid = blockIdx.x;
  int tid = threadIdx.x;
  int w = tid >> 6, l = tid & 63;
  int rf = w & 1, hc = w >> 1;
  int lc = l & 31, lh = l >> 5;
  int sr = tid >> 2, sg = tid & 3;
  f16v z16 = {0,0,0,0,0,0,0,0,0,0,0,0,0,0,0,0};
  uint4 zero4 = {0,0,0,0};

  if (bid < 128){
    // ===== GRU2: plain bf16, 32x32x16 =====
    unsigned short* As = (unsigned short*)smem;            // [64][40]
    unsigned short* Bs = (unsigned short*)smem + 64*40;    // [192][40]
    int ct = bid & 7, rt = bid >> 3;
    int rowBase = rt << 6, colBase = ct << 6;
    bool keep = mask_t[rowBase + sr] != 0.f;
    f16v acc[3] = {z16, z16, z16};

    uint4 pA;
    bf16x8 pB[3];
    {
      pA = *(const uint4*)&hp2b[(size_t)(rowBase + sr)*HH + sg*8];
      #pragma unroll
      for (int i=0;i<3;++i){
        int unit = i*256 + tid, brow = unit >> 2, q = unit & 3;
        int g = brow >> 6, c = brow & 63;
        pB[i] = *(const bf16x8*)&Wh2T[(size_t)(g*HH + colBase + c)*HH + q*8];
      }
    }
    for (int k0 = 0; k0 < HH; k0 += 32){
      __syncthreads();
      {
        *(uint4*)&As[sr*40 + sg*8] = keep ? pA : zero4;
        #pragma unroll
        for (int i=0;i<3;++i){
          int unit = i*256 + tid, brow = unit >> 2, q = unit & 3;
          *(bf16x8*)&Bs[brow*40 + q*8] = pB[i];
        }
      }
      __syncthreads();
      if (k0 + 32 < HH){
        pA = *(const uint4*)&hp2b[(size_t)(rowBase + sr)*HH + k0 + 32 + sg*8];
        #pragma unroll
        for (int i=0;i<3;++i){
          int unit = i*256 + tid, brow = unit >> 2, q = unit & 3;
          int g = brow >> 6, c = brow & 63;
          pB[i] = *(const bf16x8*)&Wh2T[(size_t)(g*HH + colBase + c)*HH + k0 + 32 + q*8];
        }
      }
      #pragma unroll
      for (int kc=0;kc<32;kc+=16){
        bf16x8 a = *(const bf16x8*)&As[(rf*32 + lc)*40 + kc + lh*8];
        #pragma unroll
        for (int g=0; g<3; ++g){
          bf16x8 b = *(const bf16x8*)&Bs[(g*64 + hc*32 + lc)*40 + kc + lh*8];
          acc[g] = __builtin_amdgcn_mfma_f32_32x32x16_bf16(a, b, acc[g], 0,0,0);
        }
      }
    }
    int col = colBase + hc*32 + lc;
    float bn = bhn2[col];
    #pragma unroll
    for (int r=0;r<16;++r){
      int row = rowBase + rf*32 + (r&3) + 8*(r>>2) + 4*lh;
      size_t gb = (size_t)row*H3 + col;
      float g_r = __builtin_nontemporal_load(&gi2[gb]);
      float g_z = __builtin_nontemporal_load(&gi2[gb + HH]);
      float g_n = __builtin_nontemporal_load(&gi2[gb + 2*HH]);
      float hv  = hp2[(size_t)row*HH + col] * mask_t[row];   // exact (branch-2 margin)
      float rg = sigm(g_r + acc[0][r]);
      float zg = sigm(g_z + acc[1][r]);
      float ng = tanhf(g_n + rg*(acc[2][r] + bn));
      float o  = (1.f - zg)*ng + zg*hv;
      size_t oo = (size_t)row*HH + col;
      ho2[oo]  = o;
      ho2b[oo] = f2bf(o);              // CACHED store: read by next step's staging
    }
  } else {
    // ===== GRU1: split hi/lo, 32x32x16, ~fp32 precision =====
    unsigned short* AsH = (unsigned short*)smem;             // [64][40]
    unsigned short* AsL = AsH + 64*40;
    unsigned short* BsH = AsL + 64*40;                       // [192][40]
    unsigned short* BsL = BsH + 192*40;
    int bidp = bid - 128;
    int ct = bidp & 7, rt = bidp >> 3;
    int rowBase = rt << 6, colBase = ct << 6;
    int capk = colBase + hc*32;
    bool keep = mask_t[rowBase + sr] != 0.f;
    f16v acc[3] = {z16, z16, z16};
    float hval[16];

    uint4 pAh, pAl;
    bf16x8 pBH[3], pBL[3];
    {
      size_t sA = (size_t)(rowBase + sr)*HH + sg*8;
      pAh = *(const uint4*)&hp1h[sA];
      pAl = *(const uint4*)&hp1l[sA];
      #pragma unroll
      for (int i=0;i<3;++i){
        int unit = i*256 + tid, brow = unit >> 2, q = unit & 3;
        int g = brow >> 6, c = brow & 63;
        size_t src = (size_t)(g*HH + colBase + c)*HH + q*8;
        pBH[i] = *(const bf16x8*)&Wh1TH[src];
        pBL[i] = *(const bf16x8*)&Wh1TL[src];
      }
    }
    for (int k0 = 0; k0 < HH; k0 += 32){
      __syncthreads();
      {
        *(uint4*)&AsH[sr*40 + sg*8] = keep ? pAh : zero4;
        *(uint4*)&AsL[sr*40 + sg*8] = keep ? pAl : zero4;
        #pragma unroll
        for (int i=0;i<3;++i){
          int unit = i*256 + tid, brow = unit >> 2, q = unit & 3;
          *(bf16x8*)&BsH[brow*40 + q*8] = pBH[i];
          *(bf16x8*)&BsL[brow*40 + q*8] = pBL[i];
        }
      }
      __syncthreads();
      if (k0 + 32 < HH){
        size_t sA = (size_t)(rowBase + sr)*HH + k0 + 32 + sg*8;
        pAh = *(const uint4*)&hp1h[sA];
        pAl = *(const uint4*)&hp1l[sA];
        #pragma unroll
        for (int i=0;i<3;++i){
          int unit = i*256 + tid, brow = unit >> 2, q = unit & 3;
          int g = brow >> 6, c = brow & 63;
          size_t src = (size_t)(g*HH + colBase + c)*HH + k0 + 32 + q*8;
          pBH[i] = *(const bf16x8*)&Wh1TH[src];
          pBL[i] = *(const bf16x8*)&Wh1TL[src];
        }
      }
      if (k0 == capk){                 // masked h_prev at own columns (hi+lo, err ~2^-17)
        #pragma unroll
        for (int r=0;r<16;++r){
          int rl = rf*32 + (r&3) + 8*(r>>2) + 4*lh;
          hval[r] = bf2f(AsH[rl*40 + lc]) + bf2f(AsL[rl*40 + lc]);
        }
      }
      #pragma unroll
      for (int kc=0;kc<32;kc+=16){
        bf16x8 aH = *(const bf16x8*)&AsH[(rf*32 + lc)*40 + kc + lh*8];
        bf16x8 aL = *(const bf16x8*)&AsL[(rf*32 + lc)*40 + kc + lh*8];
        #pragma unroll
        for (int g=0; g<3; ++g){
          int brow = (g*64 + hc*32 + lc)*40 + kc + lh*8;
          bf16x8 bH = *(const bf16x8*)&BsH[brow];
          bf16x8 bL = *(const bf16x8*)&BsL[brow];
          acc[g] = __builtin_amdgcn_mfma_f32_32x32x16_bf16(aH, bH, acc[g], 0,0,0);
          acc[g] = __builtin_amdgcn_mfma_f32_32x32x16_bf16(aH, bL, acc[g], 0,0,0);
          acc[g] = __builtin_amdgcn_mfma_f32_32x32x16_bf16(aL, bH, acc[g], 0,0,0);
        }
      }
    }
    int col = colBase + hc*32 + lc;
    float bn = bhn1[col];
    #pragma unroll
    for (int r=0;r<16;++r){
      int row = rowBase + rf*32 + (r&3) + 8*(r>>2) + 4*lh;
      size_t gb = (size_t)row*H3 + col;
      float g_r = __builtin_nontemporal_load(&gi1[gb]);
      float g_z = __builtin_nontemporal_load(&gi1[gb + HH]);
      float g_n = __builtin_nontemporal_load(&gi1[gb + 2*HH]);
      float rg = sigm(g_r + acc[0][r]);
      float zg = sigm(g_z + acc[1][r]);
      float ng = tanhf(g_n + rg*(acc[2][r] + bn));
      float o  = (1.f - zg)*ng + zg*hval[r];
      size_t oo = (size_t)row*HH + col;
      unsigned short hi = f2bf(o);     // CACHED stores: read by next step's staging
      y1h[oo] = hi;
      y1l[oo] = f2bf(o - bf2f(hi));
    }
  }
}

// ---------------- logits + first-max argmax (fully unrolled) ----------------
__global__ __launch_bounds__(256) void k_logits(const float* __restrict__ ae2,
    const float* __restrict__ e, float* __restrict__ out_logits, int* __restrict__ argk, int t0)
{
  __shared__ float es[KK*SS];
  int tid = threadIdx.x;
  for (int i=0;i<4;++i) es[tid + i*256] = e[tid + i*256];
  __syncthreads();
  int g = blockIdx.x*256 + tid;
  int t = t0 + (g >> 10), j = g & 1023;
  const float* arow = &ae2[(size_t)g * SS];
  float a[SS];
  #pragma unroll
  for (int i=0;i<16;++i){ float4 v = ((const float4*)arow)[i]; a[4*i]=v.x; a[4*i+1]=v.y; a[4*i+2]=v.z; a[4*i+3]=v.w; }
  float lg[KK];
  float best = -INFINITY; int bk = 0;
  #pragma unroll
  for (int k=0;k<KK;++k){
    float s2 = 0.f;
    #pragma unroll
    for (int s=0;s<SS;++s) s2 += a[s]*es[k*SS+s];
    lg[k] = s2;
    if (s2 > best){ best = s2; bk = k; }
  }
  int n = j >> 7, b = j & 127;
  size_t ob = ((size_t)((t*BB + b)*NN + n)) * KK;
  #pragma unroll
  for (int k4=0;k4<4;++k4)
    *(float4*)&out_logits[ob + k4*4] = make_float4(lg[k4*4],lg[k4*4+1],lg[k4*4+2],lg[k4*4+3]);
  argk[(t*BB + b)*NN + n] = bk;   // (b,n)-major: matches reference's prob/q index quirk
}

// ---------------- q selection (chunked) ----------------
__global__ __launch_bounds__(64) void k_qsel(const float* __restrict__ y2,
    const float* __restrict__ w1, const float* __restrict__ b1,
    const int* __restrict__ argk, float* __restrict__ outq)
{
  __shared__ float yr[HH];
  __shared__ float part[64];
  int bj = blockIdx.x;
  int tid = threadIdx.x;
  const float4* row4 = (const float4*)&y2[(size_t)bj*HH];
  ((float4*)yr)[tid]    = row4[tid];
  ((float4*)yr)[tid+64] = row4[tid+64];
  __syncthreads();
  int k = argk[bj];
  int a = tid & 15, q4 = tid >> 4;
  const float* wp = &w1[(size_t)k*HH*AA + a];
  float s = 0.f;
  int h0 = q4*128;
  #pragma unroll 8
  for (int h=h0; h<h0+128; ++h) s += yr[h]*wp[(size_t)h*AA];
  part[tid] = s;
  __syncthreads();
  if (q4 == 0){
    float v = part[a] + part[a+16] + part[a+32] + part[a+48] + b1[k*AA + a];
    outq[(size_t)bj*AA + a] = v;
  }
}

// ---------------- orchestration ----------------
extern "C" void kernel_launch(void* const* d_in, const int* in_sizes, int n_in,
                              void* d_out, int out_size, void* d_ws, size_t ws_size,
                              hipStream_t stream)
{
  (void)in_sizes; (void)n_in; (void)out_size;
  const float* h1     = (const float*)d_in[0];
  const float* h2     = (const float*)d_in[1];
  const float* obs    = (const float*)d_in[2];
  const unsigned char* done_raw = (const unsigned char*)d_in[3];
  const float* W_embed=(const float*)d_in[4];  const float* b_embed=(const float*)d_in[5];
  const float* Wi1    =(const float*)d_in[6];  const float* bi1    =(const float*)d_in[7];
  const float* Wh1    =(const float*)d_in[8];  const float* bhn1   =(const float*)d_in[9];
  const float* W_sub  =(const float*)d_in[10]; const float* b_sub  =(const float*)d_in[11];
  const float* W_e1   =(const float*)d_in[12]; const float* b_e1   =(const float*)d_in[13];
  const float* W_e2   =(const float*)d_in[14]; const float* b_e2   =(const float*)d_in[15];
  const float* W_pol  =(const float*)d_in[16]; const float* b_pol  =(const float*)d_in[17];
  const float* Wi2    =(const float*)d_in[18]; const float* bi2    =(const float*)d_in[19];
  const float* Wh2    =(const float*)d_in[20]; const float* bhn2   =(const float*)d_in[21];
  const float* W_w1   =(const float*)d_in[22]; const float* b_w1   =(const float*)d_in[23];
  const float* W_b1   =(const float*)d_in[24]; const float* b_b1   =(const float*)d_in[25];

  float* out    = (float*)d_out;
  float* outHT1 = out;
  float* outHT2 = out + (size_t)NB*HH;
  float* outQ   = out + 2ull*NB*HH;
  float* outLG  = outQ + (size_t)TT*NB*AA;
  float* outSE  = outLG + (size_t)TT*BB*NN*KK;

  // ---- adaptive chunk size (float units) ----
  const size_t fixed_f = (size_t)TT*NB + 1024
                       + (size_t)KK*HH*AA + 256 + (size_t)TT*NB + 64
                       + 2ull*NB*HH/2
                       + 2ull*NB*HH/2
                       + 2ull*DD*HH/2 * 2
                       + 4ull*H3*HH
                       + (size_t)HH*SS;
  const size_t per_t_f = (size_t)NB*(HH + 2*H3 + SS)
                       + (size_t)NB*(HH/2 + DD + HH);
  int CH = 64;
  while (CH > 1 && (fixed_f + per_t_f*(size_t)CH)*4 > ws_size) CH >>= 1;

  float* buf2   = (float*)d_ws;                        // y2 chunk (f32): CH*NB*HH
  float* gbuf1  = buf2   + (size_t)CH*NB*HH;           // gi1 chunk
  float* gbuf2  = gbuf1  + (size_t)CH*NB*H3;           // gi2 chunk
  float* ae2buf = gbuf2  + (size_t)CH*NB*H3;           // CH*NB*SS
  float* maskp  = ae2buf + (size_t)CH*NB*SS;
  float* ws_e   = maskp  + (size_t)TT*NB;
  float* ws_w1  = ws_e   + 1024;
  float* ws_b1  = ws_w1  + (size_t)KK*HH*AA;
  int*   ws_argk= (int*)(ws_b1 + 256);
  int*   ws_flag= (int*)(ws_argk + (size_t)TT*NB);
  unsigned short* buf2bf = (unsigned short*)(ws_flag + 64);   // CH*NB*HH (sp bf16)
  unsigned short* obs_h  = buf2bf + (size_t)CH*NB*HH;         // CH*NB*DD
  unsigned short* obs_l  = obs_h  + (size_t)CH*NB*DD;
  unsigned short* y1_h   = obs_l  + (size_t)CH*NB*DD;         // CH*NB*HH (y1 pair = h1 carry)
  unsigned short* y1_l   = y1_h   + (size_t)CH*NB*HH;
  unsigned short* hl1h   = y1_l   + (size_t)CH*NB*HH;         // NB*HH chunk-carry pair
  unsigned short* hl1l   = hl1h   + (size_t)NB*HH;
  unsigned short* y2b0   = hl1l   + (size_t)NB*HH;            // GRU2 bf16 h, 2 slots
  unsigned short* y2b1   = y2b0   + (size_t)NB*HH;
  unsigned short* wembt_h= y2b1   + (size_t)NB*HH;
  unsigned short* wembt_l= wembt_h+ (size_t)HH*DD;
  unsigned short* wpolt_h= wembt_l+ (size_t)HH*DD;
  unsigned short* wpolt_l= wpolt_h+ (size_t)HH*DD;
  unsigned short* wi1t_h = wpolt_l+ (size_t)HH*DD;
  unsigned short* wi1t_l = wi1t_h + (size_t)H3*HH;
  unsigned short* wi2t_h = wi1t_l + (size_t)H3*HH;
  unsigned short* wi2t_l = wi2t_h + (size_t)H3*HH;
  unsigned short* wh1t_h = wi2t_l + (size_t)H3*HH;
  unsigned short* wh1t_l = wh1t_h + (size_t)H3*HH;
  unsigned short* wh2t_h = wh1t_l + (size_t)H3*HH;
  unsigned short* wh2t_l = wh2t_h + (size_t)H3*HH;
  unsigned short* wsubt_h= wh2t_l + (size_t)H3*HH;
  unsigned short* wsubt_l= wsubt_h+ (size_t)SS*HH;
  unsigned short* y2bslot[2] = { y2b0, y2b1 };

  // phase 0
  k_detect<<<1,256,0,stream>>>(done_raw, ws_flag);
  k_mask<<<TT*NB/256,256,0,stream>>>(done_raw, ws_flag, maskp);
  k_e<<<1,256,0,stream>>>(W_e1,b_e1,W_e2,b_e2,ws_e);
  k_w1b1<<<128,256,0,stream>>>(ws_e,W_w1,b_w1,W_b1,b_b1,ws_w1,ws_b1);
  k_se<<<2048,256,0,stream>>>(ws_e,outSE);
  k_tsplit<<<dim3(16,4),256,0,stream>>>(W_embed, wembt_h, wembt_l, DD, HH);
  k_tsplit<<<dim3(16,4),256,0,stream>>>(W_pol,   wpolt_h, wpolt_l, DD, HH);
  k_tsplit<<<dim3(48,16),256,0,stream>>>(Wi1, wi1t_h, wi1t_l, HH, H3);
  k_tsplit<<<dim3(48,16),256,0,stream>>>(Wi2, wi2t_h, wi2t_l, HH, H3);
  k_tsplit<<<dim3(48,16),256,0,stream>>>(Wh1, wh1t_h, wh1t_l, HH, H3);
  k_tsplit<<<dim3(48,16),256,0,stream>>>(Wh2, wh2t_h, wh2t_l, HH, H3);
  k_tsplit<<<dim3(2,16),256,0,stream>>>(W_sub, wsubt_h, wsubt_l, HH, SS);
  k_split_cast<<<NB*HH/8/256,256,0,stream>>>(h1, hl1h, hl1l, NB*HH/8);   // GRU1 carry pair
  k_cast_bf16<<<NB*HH/8/256,256,0,stream>>>(h2, y2b1, NB*HH/8);          // GRU2 carry (gstep=0 reads slot 1)

  dim3 thr(256);
  const int NCH = TT / CH;
  for (int c = 0; c < NCH; ++c){
    int t0 = c * CH;
    int M = CH*NB;
    const float* obs_c = obs + (size_t)t0*NB*DD;
    k_split_cast<<<(M*DD/8+255)/256,256,0,stream>>>(obs_c, obs_h, obs_l, M*DD/8);
    // embed1 writes ae pair into y1 slots; gi1 consumes it immediately (stream-ordered, then scan overwrites)
    mfma_gemm<DD,1,128,1,2><<<dim3(HH/128, M/128),thr,0,stream>>>(
        obs_h, obs_l, wembt_h, wembt_l, b_embed, nullptr, y1_h, y1_l, HH);
    mfma_gemm<HH,1,128,0,0><<<dim3(H3/128, M/128),thr,0,stream>>>(
        y1_h, y1_l, wi1t_h, wi1t_l, bi1, gbuf1, nullptr, nullptr, H3);
    mfma_gemm<DD,0,128,1,1><<<dim3(HH/128, M/128),thr,0,stream>>>(
        obs_h, obs_h, wpolt_h, wpolt_h, b_pol, nullptr, buf2bf, nullptr, HH);
    mfma_gemm<HH,0,128,0,0><<<dim3(H3/128, M/128),thr,0,stream>>>(
        buf2bf, buf2bf, wi2t_h, wi2t_h, bi2, gbuf2, nullptr, nullptr, H3);
    // dual-GRU scan: h carried as bf16 (pair for GRU1, single for GRU2)
    for (int lt = 0; lt < CH; ++lt){
      int gstep = t0 + lt;
      const unsigned short* hp1h = (lt == 0) ? hl1h : (y1_h + (size_t)(lt-1)*NB*HH);
      const unsigned short* hp1l = (lt == 0) ? hl1l : (y1_l + (size_t)(lt-1)*NB*HH);
      const float* hp2 = (c == 0 && lt == 0) ? h2 :
                         (lt == 0 ? buf2 + (size_t)(CH-1)*NB*HH : buf2 + (size_t)(lt-1)*NB*HH);
      const unsigned short* hp2b = y2bslot[(gstep+1)&1];
      gru_step_mix4<<<256, 256, 0, stream>>>(hp1h, hp1l, hp2, hp2b,
                                             gbuf1 + (size_t)lt*NB*H3, gbuf2 + (size_t)lt*NB*H3,
                                             wh1t_h, wh1t_l, wh2t_h, bhn1, bhn2,
                                             maskp + (size_t)gstep*NB,
                                             buf2 + (size_t)lt*NB*HH, y2bslot[gstep&1],
                                             y1_h + (size_t)lt*NB*HH, y1_l + (size_t)lt*NB*HH);
    }
    // chunk carry for GRU1 (copy last y1 pair slot before next chunk's embed1 overwrites y1)
    k_copy<<<256,256,0,stream>>>((const float*)(y1_h + (size_t)(CH-1)*NB*HH), (float*)hl1h, NB*HH/8);
    k_copy<<<256,256,0,stream>>>((const float*)(y1_l + (size_t)(CH-1)*NB*HH), (float*)hl1l, NB*HH/8);
    // tails: ae2 via split MFMA, logits, qsel
    mfma_gemm<HH,1,64,0,0><<<dim3(1, M/128),thr,0,stream>>>(
        y1_h, y1_l, wsubt_h, wsubt_l, b_sub, ae2buf, nullptr, nullptr, SS);
    k_logits<<<M/256,256,0,stream>>>(ae2buf, ws_e, outLG, ws_argk, t0);
    k_qsel<<<M,64,0,stream>>>(buf2, ws_w1, ws_b1, ws_argk + (size_t)t0*NB, outQ + (size_t)t0*NB*AA);
  }
  k_merge<<<NB*HH/8/256,256,0,stream>>>(hl1h, hl1l, outHT1, NB*HH/8);
  k_copy<<<512,256,0,stream>>>(buf2 + (size_t)(CH-1)*NB*HH, outHT2, NB*HH/4);
}

// Round 14
// 2986.750 us; speedup vs baseline: 1.1243x; 1.1058x over previous
//
#include <hip/hip_runtime.h>
#include <hip/hip_bf16.h>
#include <math.h>

#define TT 64
#define NN 8
#define BB 128
#define DD 128
#define HH 512
#define SS 64
#define KK 16
#define AA 16
#define NB 1024
#define H3 (3*HH)       /* 1536 */

typedef float f4v  __attribute__((ext_vector_type(4)));
typedef float f16v __attribute__((ext_vector_type(16)));
typedef short bf16x8 __attribute__((ext_vector_type(8)));

__device__ __forceinline__ float sigm(float x){ return 1.0f/(1.0f+expf(-x)); }
__device__ __forceinline__ unsigned short f2bf(float f){
  unsigned u = __float_as_uint(f);
  u += 0x7FFF + ((u >> 16) & 1);          // round-to-nearest-even
  return (unsigned short)(u >> 16);
}
__device__ __forceinline__ float bf2f(unsigned short h){
  return __uint_as_float(((unsigned)h) << 16);
}

// ---------------- done-layout detection + mask expansion ----------------
__global__ __launch_bounds__(256) void k_detect(const unsigned char* __restrict__ raw,
                                                int* __restrict__ flag)
{
  __shared__ int cA, cB;
  if (threadIdx.x == 0){ cA = 0; cB = 0; }
  __syncthreads();
  int a = 0, b = 0;
  for (int i = threadIdx.x; i < TT*NB; i += 256){
    unsigned char v = raw[i];
    if (v > 1) a++;
    if ((i & 3) != 0 && v != 0) b++;
  }
  atomicAdd(&cA, a); atomicAdd(&cB, b);
  __syncthreads();
  if (threadIdx.x == 0) *flag = (cB == 0) ? 0 : (cA == 0 ? 1 : 2);
}

__global__ __launch_bounds__(256) void k_mask(const unsigned char* __restrict__ raw,
                                              const int* __restrict__ flag,
                                              float* __restrict__ mask)
{
  int i = blockIdx.x*256 + threadIdx.x;
  if (i >= TT*NB) return;
  int f = *flag;
  int v;
  if (f == 1)      v = (int)raw[i];
  else if (f == 0) v = ((const int*)raw)[i];
  else             v = (((const float*)raw)[i] != 0.0f);
  mask[i] = v ? 0.f : 1.f;   // 0 => reset carry
}

// ---------------- small setup kernels ----------------

__global__ __launch_bounds__(256) void k_e(const float* __restrict__ W_e1, const float* __restrict__ b_e1,
                                           const float* __restrict__ W_e2, const float* __restrict__ b_e2,
                                           float* __restrict__ e_out)
{
  __shared__ float r1[KK*SS];
  int tid = threadIdx.x;
  for (int i=0;i<4;++i){ int l = tid + i*256; float v = W_e1[l] + b_e1[l & 63]; r1[l] = v > 0.f ? v : 0.f; }
  __syncthreads();
  for (int i=0;i<4;++i){
    int l = tid + i*256; int k = l >> 6, s = l & 63;
    float acc = b_e2[s];
    #pragma unroll 8
    for (int sp=0; sp<64; ++sp) acc += r1[k*64+sp] * W_e2[sp*64 + s];
    e_out[l] = tanhf(acc);
  }
}

__global__ __launch_bounds__(256) void k_w1b1(const float* __restrict__ e, const float* __restrict__ W_w1,
                                              const float* __restrict__ b_w1, const float* __restrict__ W_b1,
                                              const float* __restrict__ b_b1, float* __restrict__ w1,
                                              float* __restrict__ b1)
{
  __shared__ float es[KK*SS];
  int tid = threadIdx.x;
  for (int i=0;i<4;++i) es[tid + i*256] = e[tid + i*256];
  __syncthreads();
  for (int i=0;i<4;++i){
    int l = blockIdx.x*1024 + tid + i*256;
    int k = l >> 13, m = l & 8191;
    float acc = b_w1[m];
    #pragma unroll 8
    for (int s=0;s<64;++s) acc += es[k*64+s] * W_w1[(size_t)s*8192 + m];
    w1[l] = acc;
  }
  if (blockIdx.x == 0){
    int k = tid >> 4, a = tid & 15;
    float acc = b_b1[a];
    #pragma unroll 8
    for (int s=0;s<64;++s) acc += es[k*64+s] * W_b1[s*16 + a];
    b1[tid] = acc;
  }
}

__global__ __launch_bounds__(256) void k_se(const float* __restrict__ e, float* __restrict__ outse)
{
  __shared__ float4 es[256];
  es[threadIdx.x] = ((const float4*)e)[threadIdx.x];
  __syncthreads();
  const int total4 = TT*BB*KK*SS/4;
  for (int i = blockIdx.x*256 + threadIdx.x; i < total4; i += gridDim.x*256)
    ((float4*)outse)[i] = es[i & 255];
}

__global__ void k_copy(const float* __restrict__ src, float* __restrict__ dst, int n4)
{
  int i = blockIdx.x*blockDim.x + threadIdx.x;
  if (i < n4) ((float4*)dst)[i] = ((const float4*)src)[i];
}

// merge hi/lo bf16 pair -> f32
__global__ void k_merge(const unsigned short* __restrict__ h, const unsigned short* __restrict__ l,
                        float* __restrict__ o, int n8)
{
  int i = blockIdx.x*blockDim.x + threadIdx.x;
  if (i >= n8) return;
  uint4 vh = *(const uint4*)&h[(size_t)i*8];
  uint4 vl = *(const uint4*)&l[(size_t)i*8];
  const unsigned short* ph = (const unsigned short*)&vh;
  const unsigned short* pl = (const unsigned short*)&vl;
  float4 o0, o1;
  o0.x = bf2f(ph[0])+bf2f(pl[0]); o0.y = bf2f(ph[1])+bf2f(pl[1]);
  o0.z = bf2f(ph[2])+bf2f(pl[2]); o0.w = bf2f(ph[3])+bf2f(pl[3]);
  o1.x = bf2f(ph[4])+bf2f(pl[4]); o1.y = bf2f(ph[5])+bf2f(pl[5]);
  o1.z = bf2f(ph[6])+bf2f(pl[6]); o1.w = bf2f(ph[7])+bf2f(pl[7]);
  float4* d = (float4*)&o[(size_t)i*8];
  d[0] = o0; d[1] = o1;
}

// bf16 -> f32 expand
__global__ void k_expand(const unsigned short* __restrict__ src, float* __restrict__ dst, int n8)
{
  int i = blockIdx.x*blockDim.x + threadIdx.x;
  if (i >= n8) return;
  uint4 v = *(const uint4*)&src[(size_t)i*8];
  const unsigned short* p = (const unsigned short*)&v;
  float4 o0 = make_float4(bf2f(p[0]),bf2f(p[1]),bf2f(p[2]),bf2f(p[3]));
  float4 o1 = make_float4(bf2f(p[4]),bf2f(p[5]),bf2f(p[6]),bf2f(p[7]));
  float4* d = (float4*)&dst[(size_t)i*8];
  d[0] = o0; d[1] = o1;
}

// f32 -> bf16 flat cast
__global__ void k_cast_bf16(const float* __restrict__ src, unsigned short* __restrict__ dst, int n8)
{
  int i = blockIdx.x*blockDim.x + threadIdx.x;
  if (i >= n8) return;
  const float4* s = (const float4*)(src + (size_t)i*8);
  float4 a = s[0], b = s[1];
  union { unsigned short u[8]; uint4 v; } p;
  p.u[0]=f2bf(a.x); p.u[1]=f2bf(a.y); p.u[2]=f2bf(a.z); p.u[3]=f2bf(a.w);
  p.u[4]=f2bf(b.x); p.u[5]=f2bf(b.y); p.u[6]=f2bf(b.z); p.u[7]=f2bf(b.w);
  *(uint4*)&dst[(size_t)i*8] = p.v;
}

// generic transpose + split: W [Kd][Nc] f32 -> WTh/WTl [Nc][Kd] bf16
__global__ __launch_bounds__(256) void k_tsplit(const float* __restrict__ W,
                                                unsigned short* __restrict__ WTh,
                                                unsigned short* __restrict__ WTl,
                                                int Kd, int Nc)
{
  __shared__ float t[32][33];
  int n0 = blockIdx.x * 32;
  int k0 = blockIdx.y * 32;
  int c = threadIdx.x & 31, r8 = threadIdx.x >> 5;
  for (int i=0;i<4;++i){
    int r = r8 + i*8;
    t[r][c] = W[(size_t)(k0+r)*Nc + n0 + c];
  }
  __syncthreads();
  for (int i=0;i<4;++i){
    int nr = r8 + i*8;
    float v = t[c][nr];
    unsigned short hi = f2bf(v);
    WTh[(size_t)(n0+nr)*Kd + k0 + c] = hi;
    WTl[(size_t)(n0+nr)*Kd + k0 + c] = f2bf(v - bf2f(hi));
  }
}

// f32 -> (hi, lo) bf16 flat split-cast
__global__ void k_split_cast(const float* __restrict__ src,
                             unsigned short* __restrict__ dh,
                             unsigned short* __restrict__ dl, int n8)
{
  int i = blockIdx.x*blockDim.x + threadIdx.x;
  if (i >= n8) return;
  const float4* s = (const float4*)(src + (size_t)i*8);
  float4 a = s[0], b = s[1];
  float x[8] = {a.x,a.y,a.z,a.w,b.x,b.y,b.z,b.w};
  union { unsigned short u[8]; uint4 v; } ph, pl;
  #pragma unroll
  for (int j=0;j<8;++j){
    unsigned short hi = f2bf(x[j]);
    ph.u[j] = hi;
    pl.u[j] = f2bf(x[j] - bf2f(hi));
  }
  *(uint4*)&dh[(size_t)i*8] = ph.v;
  *(uint4*)&dl[(size_t)i*8] = pl.v;
}

// ---------------- unified MFMA GEMM (validated round 10) ----------------
template<int KD, int SPLIT, int NTILE, int RELU, int OUTMODE>
__global__ __launch_bounds__(256) void mfma_gemm(
    const unsigned short* Ah, const unsigned short* Al,
    const unsigned short* Bh, const unsigned short* Bl,
    const float* __restrict__ bias,
    float* C, unsigned short* Chi, unsigned short* Clo, int Nstride)
{
  constexpr int NFC = NTILE/16;
  __shared__ __align__(16) unsigned short AsH[128*40];
  __shared__ __align__(16) unsigned short BsH[NTILE*40];
  __shared__ __align__(16) unsigned short AsL[SPLIT ? 128*40 : 8];
  __shared__ __align__(16) unsigned short BsL[SPLIT ? NTILE*40 : 8];
  int tid = threadIdx.x;
  int w = tid >> 6, l = tid & 63;
  int lr = l & 15, lk = (l >> 4) * 8, lq = l >> 4;
  int rowBase = blockIdx.y * 128, colBase = blockIdx.x * NTILE;
  f4v acc[2][NFC];
  f4v z = {0.f,0.f,0.f,0.f};
  #pragma unroll
  for (int i=0;i<2;++i)
    #pragma unroll
    for (int j=0;j<NFC;++j) acc[i][j] = z;

  for (int k0 = 0; k0 < KD; k0 += 32){
    {
      int r = tid >> 1, half = tid & 1;
      size_t src = (size_t)(rowBase + r)*KD + k0 + half*16;
      bf16x8* dA = (bf16x8*)&AsH[r*40 + half*16];
      dA[0] = *(const bf16x8*)&Ah[src];
      dA[1] = *(const bf16x8*)&Ah[src + 8];
      if (SPLIT){
        bf16x8* dL = (bf16x8*)&AsL[r*40 + half*16];
        dL[0] = *(const bf16x8*)&Al[src];
        dL[1] = *(const bf16x8*)&Al[src + 8];
      }
    }
    if (NTILE == 128){
      int r = tid >> 1, half = tid & 1;
      size_t src = (size_t)(colBase + r)*KD + k0 + half*16;
      bf16x8* dB = (bf16x8*)&BsH[r*40 + half*16];
      dB[0] = *(const bf16x8*)&Bh[src];
      dB[1] = *(const bf16x8*)&Bh[src + 8];
      if (SPLIT){
        bf16x8* dL = (bf16x8*)&BsL[r*40 + half*16];
        dL[0] = *(const bf16x8*)&Bl[src];
        dL[1] = *(const bf16x8*)&Bl[src + 8];
      }
    } else {   // NTILE == 64
      int r = tid >> 2, q = tid & 3;
      size_t src = (size_t)(colBase + r)*KD + k0 + q*8;
      *(bf16x8*)&BsH[r*40 + q*8] = *(const bf16x8*)&Bh[src];
      if (SPLIT)
        *(bf16x8*)&BsL[r*40 + q*8] = *(const bf16x8*)&Bl[src];
    }
    __syncthreads();
    bf16x8 aH0 = *(const bf16x8*)&AsH[(w*32 + lr)*40 + lk];
    bf16x8 aH1 = *(const bf16x8*)&AsH[(w*32 + 16 + lr)*40 + lk];
    bf16x8 aL0, aL1;
    if (SPLIT){
      aL0 = *(const bf16x8*)&AsL[(w*32 + lr)*40 + lk];
      aL1 = *(const bf16x8*)&AsL[(w*32 + 16 + lr)*40 + lk];
    }
    #pragma unroll
    for (int fc=0; fc<NFC; ++fc){
      bf16x8 bH = *(const bf16x8*)&BsH[(fc*16 + lr)*40 + lk];
      acc[0][fc] = __builtin_amdgcn_mfma_f32_16x16x32_bf16(aH0, bH, acc[0][fc], 0,0,0);
      acc[1][fc] = __builtin_amdgcn_mfma_f32_16x16x32_bf16(aH1, bH, acc[1][fc], 0,0,0);
      if (SPLIT){
        bf16x8 bL = *(const bf16x8*)&BsL[(fc*16 + lr)*40 + lk];
        acc[0][fc] = __builtin_amdgcn_mfma_f32_16x16x32_bf16(aH0, bL, acc[0][fc], 0,0,0);
        acc[1][fc] = __builtin_amdgcn_mfma_f32_16x16x32_bf16(aH1, bL, acc[1][fc], 0,0,0);
        acc[0][fc] = __builtin_amdgcn_mfma_f32_16x16x32_bf16(aL0, bH, acc[0][fc], 0,0,0);
        acc[1][fc] = __builtin_amdgcn_mfma_f32_16x16x32_bf16(aL1, bH, acc[1][fc], 0,0,0);
      }
    }
    __syncthreads();
  }
  #pragma unroll
  for (int fr=0; fr<2; ++fr){
    #pragma unroll
    for (int fc=0; fc<NFC; ++fc){
      int col = colBase + fc*16 + lr;
      float bv = bias[col];
      #pragma unroll
      for (int r=0;r<4;++r){
        int row = rowBase + w*32 + fr*16 + lq*4 + r;
        float v = acc[fr][fc][r] + bv;
        if (RELU) v = v > 0.f ? v : 0.f;
        size_t o = (size_t)row*Nstride + col;
        if (OUTMODE == 0) C[o] = v;
        else if (OUTMODE == 1) Chi[o] = f2bf(v);
        else {
          unsigned short hi = f2bf(v);
          Chi[o] = hi;
          Clo[o] = f2bf(v - bf2f(hi));
        }
      }
    }
  }
}

// ---------------- per-step GRU: 32x32x16 MFMA, LDS double-buffer, XCD-pinned ----------------
// gru = bid&1 (XCD = bid%8 => even XCDs host only GRU2, odd only GRU1 -> Wh fits per-XCD L2).
// One barrier per 32-k chunk: stage chunk k+1 into alt LDS buffer while computing chunk k.
// GRU2 carries h ONLY as bf16 (hv from staged tile); GRU1 carries hi/lo pair (~fp32).
__global__ __launch_bounds__(256) void gru_step_mix5(
    const unsigned short* __restrict__ hp1h, const unsigned short* __restrict__ hp1l,
    const unsigned short* __restrict__ hp2b,
    const float* __restrict__ gi1, const float* __restrict__ gi2,
    const unsigned short* __restrict__ Wh1TH, const unsigned short* __restrict__ Wh1TL,
    const unsigned short* __restrict__ Wh2T,
    const float* __restrict__ bhn1, const float* __restrict__ bhn2,
    const float* __restrict__ mask_t,
    unsigned short* __restrict__ y2b,
    unsigned short* __restrict__ y1h, unsigned short* __restrict__ y1l)
{
  extern __shared__ __align__(16) char smem[];
  int bid = blockIdx.x;
  int tid = threadIdx.x;
  int w = tid >> 6, l = tid & 63;
  int rf = w & 1, hc = w >> 1;
  int lc = l & 31, lh = l >> 5;
  int sr = tid >> 2, sg = tid & 3;
  int gru = bid & 1, sub = bid >> 1;
  int ct = sub & 7, rt = sub >> 3;
  int rowBase = rt << 6, colBase = ct << 6;
  int capchunk = ct*2 + hc;                 // 32-k chunk holding this wave's own h-cols
  bool keep = mask_t[rowBase + sr] != 0.f;
  f16v z16 = {0,0,0,0,0,0,0,0,0,0,0,0,0,0,0,0};
  uint4 zero4 = {0,0,0,0};

  if (gru == 0){
    // ===== GRU2: plain bf16, double-buffered =====
    f16v acc[3] = {z16, z16, z16};
    float hval[16];
    uint4 pA;
    bf16x8 pB[3];
    // prologue: chunk 0 -> buf0; prefetch chunk 1
    pA = *(const uint4*)&hp2b[(size_t)(rowBase + sr)*HH + sg*8];
    #pragma unroll
    for (int i=0;i<3;++i){
      int unit = i*256 + tid, brow = unit >> 2, q = unit & 3;
      int g = brow >> 6, c = brow & 63;
      pB[i] = *(const bf16x8*)&Wh2T[(size_t)(g*HH + colBase + c)*HH + q*8];
    }
    {
      unsigned short* As0 = (unsigned short*)smem;
      unsigned short* Bs0 = As0 + 64*40;
      *(uint4*)&As0[sr*40 + sg*8] = keep ? pA : zero4;
      #pragma unroll
      for (int i=0;i<3;++i){
        int unit = i*256 + tid, brow = unit >> 2, q = unit & 3;
        *(bf16x8*)&Bs0[brow*40 + q*8] = pB[i];
      }
    }
    pA = *(const uint4*)&hp2b[(size_t)(rowBase + sr)*HH + 32 + sg*8];
    #pragma unroll
    for (int i=0;i<3;++i){
      int unit = i*256 + tid, brow = unit >> 2, q = unit & 3;
      int g = brow >> 6, c = brow & 63;
      pB[i] = *(const bf16x8*)&Wh2T[(size_t)(g*HH + colBase + c)*HH + 32 + q*8];
    }
    __syncthreads();
    for (int ck = 0; ck < 16; ++ck){
      unsigned short* Asc = (unsigned short*)(smem + (ck&1)*20480);
      unsigned short* Bsc = Asc + 64*40;
      if (ck < 15){
        unsigned short* Asn = (unsigned short*)(smem + ((ck+1)&1)*20480);
        unsigned short* Bsn = Asn + 64*40;
        *(uint4*)&Asn[sr*40 + sg*8] = keep ? pA : zero4;
        #pragma unroll
        for (int i=0;i<3;++i){
          int unit = i*256 + tid, brow = unit >> 2, q = unit & 3;
          *(bf16x8*)&Bsn[brow*40 + q*8] = pB[i];
        }
      }
      if (ck < 14){
        int k0 = (ck+2)*32;
        pA = *(const uint4*)&hp2b[(size_t)(rowBase + sr)*HH + k0 + sg*8];
        #pragma unroll
        for (int i=0;i<3;++i){
          int unit = i*256 + tid, brow = unit >> 2, q = unit & 3;
          int g = brow >> 6, c = brow & 63;
          pB[i] = *(const bf16x8*)&Wh2T[(size_t)(g*HH + colBase + c)*HH + k0 + q*8];
        }
      }
      if (ck == capchunk){
        #pragma unroll
        for (int r=0;r<16;++r){
          int rl = rf*32 + (r&3) + 8*(r>>2) + 4*lh;
          hval[r] = bf2f(Asc[rl*40 + lc]);
        }
      }
      #pragma unroll
      for (int kc=0;kc<32;kc+=16){
        bf16x8 a = *(const bf16x8*)&Asc[(rf*32 + lc)*40 + kc + lh*8];
        #pragma unroll
        for (int g=0; g<3; ++g){
          bf16x8 b = *(const bf16x8*)&Bsc[(g*64 + hc*32 + lc)*40 + kc + lh*8];
          acc[g] = __builtin_amdgcn_mfma_f32_32x32x16_bf16(a, b, acc[g], 0,0,0);
        }
      }
      __syncthreads();
    }
    int col = colBase + hc*32 + lc;
    float bn = bhn2[col];
    #pragma unroll
    for (int r=0;r<16;++r){
      int row = rowBase + rf*32 + (r&3) + 8*(r>>2) + 4*lh;
      size_t gb = (size_t)row*H3 + col;
      float g_r = __builtin_nontemporal_load(&gi2[gb]);
      float g_z = __builtin_nontemporal_load(&gi2[gb + HH]);
      float g_n = __builtin_nontemporal_load(&gi2[gb + 2*HH]);
      float rg = sigm(g_r + acc[0][r]);
      float zg = sigm(g_z + acc[1][r]);
      float ng = tanhf(g_n + rg*(acc[2][r] + bn));
      float o  = (1.f - zg)*ng + zg*hval[r];
      y2b[(size_t)row*HH + col] = f2bf(o);
    }
  } else {
    // ===== GRU1: split hi/lo, double-buffered, ~fp32 =====
    f16v acc[3] = {z16, z16, z16};
    float hval[16];
    uint4 pAh, pAl;
    bf16x8 pBH[3], pBL[3];
    pAh = *(const uint4*)&hp1h[(size_t)(rowBase + sr)*HH + sg*8];
    pAl = *(const uint4*)&hp1l[(size_t)(rowBase + sr)*HH + sg*8];
    #pragma unroll
    for (int i=0;i<3;++i){
      int unit = i*256 + tid, brow = unit >> 2, q = unit & 3;
      int g = brow >> 6, c = brow & 63;
      size_t src = (size_t)(g*HH + colBase + c)*HH + q*8;
      pBH[i] = *(const bf16x8*)&Wh1TH[src];
      pBL[i] = *(const bf16x8*)&Wh1TL[src];
    }
    {
      unsigned short* AsH0 = (unsigned short*)smem;
      unsigned short* AsL0 = AsH0 + 64*40;
      unsigned short* BsH0 = AsL0 + 64*40;
      unsigned short* BsL0 = BsH0 + 192*40;
      *(uint4*)&AsH0[sr*40 + sg*8] = keep ? pAh : zero4;
      *(uint4*)&AsL0[sr*40 + sg*8] = keep ? pAl : zero4;
      #pragma unroll
      for (int i=0;i<3;++i){
        int unit = i*256 + tid, brow = unit >> 2, q = unit & 3;
        *(bf16x8*)&BsH0[brow*40 + q*8] = pBH[i];
        *(bf16x8*)&BsL0[brow*40 + q*8] = pBL[i];
      }
    }
    pAh = *(const uint4*)&hp1h[(size_t)(rowBase + sr)*HH + 32 + sg*8];
    pAl = *(const uint4*)&hp1l[(size_t)(rowBase + sr)*HH + 32 + sg*8];
    #pragma unroll
    for (int i=0;i<3;++i){
      int unit = i*256 + tid, brow = unit >> 2, q = unit & 3;
      int g = brow >> 6, c = brow & 63;
      size_t src = (size_t)(g*HH + colBase + c)*HH + 32 + q*8;
      pBH[i] = *(const bf16x8*)&Wh1TH[src];
      pBL[i] = *(const bf16x8*)&Wh1TL[src];
    }
    __syncthreads();
    for (int ck = 0; ck < 16; ++ck){
      unsigned short* AsHc = (unsigned short*)(smem + (ck&1)*40960);
      unsigned short* AsLc = AsHc + 64*40;
      unsigned short* BsHc = AsLc + 64*40;
      unsigned short* BsLc = BsHc + 192*40;
      if (ck < 15){
        unsigned short* AsHn = (unsigned short*)(smem + ((ck+1)&1)*40960);
        unsigned short* AsLn = AsHn + 64*40;
        unsigned short* BsHn = AsLn + 64*40;
        unsigned short* BsLn = BsHn + 192*40;
        *(uint4*)&AsHn[sr*40 + sg*8] = keep ? pAh : zero4;
        *(uint4*)&AsLn[sr*40 + sg*8] = keep ? pAl : zero4;
        #pragma unroll
        for (int i=0;i<3;++i){
          int unit = i*256 + tid, brow = unit >> 2, q = unit & 3;
          *(bf16x8*)&BsHn[brow*40 + q*8] = pBH[i];
          *(bf16x8*)&BsLn[brow*40 + q*8] = pBL[i];
        }
      }
      if (ck < 14){
        int k0 = (ck+2)*32;
        pAh = *(const uint4*)&hp1h[(size_t)(rowBase + sr)*HH + k0 + sg*8];
        pAl = *(const uint4*)&hp1l[(size_t)(rowBase + sr)*HH + k0 + sg*8];
        #pragma unroll
        for (int i=0;i<3;++i){
          int unit = i*256 + tid, brow = unit >> 2, q = unit & 3;
          int g = brow >> 6, c = brow & 63;
          size_t src = (size_t)(g*HH + colBase + c)*HH + k0 + q*8;
          pBH[i] = *(const bf16x8*)&Wh1TH[src];
          pBL[i] = *(const bf16x8*)&Wh1TL[src];
        }
      }
      if (ck == capchunk){
        #pragma unroll
        for (int r=0;r<16;++r){
          int rl = rf*32 + (r&3) + 8*(r>>2) + 4*lh;
          hval[r] = bf2f(AsHc[rl*40 + lc]) + bf2f(AsLc[rl*40 + lc]);
        }
      }
      #pragma unroll
      for (int kc=0;kc<32;kc+=16){
        bf16x8 aH = *(const bf16x8*)&AsHc[(rf*32 + lc)*40 + kc + lh*8];
        bf16x8 aL = *(const bf16x8*)&AsLc[(rf*32 + lc)*40 + kc + lh*8];
        #pragma unroll
        for (int g=0; g<3; ++g){
          int brow = (g*64 + hc*32 + lc)*40 + kc + lh*8;
          bf16x8 bH = *(const bf16x8*)&BsHc[brow];
          bf16x8 bL = *(const bf16x8*)&BsLc[brow];
          acc[g] = __builtin_amdgcn_mfma_f32_32x32x16_bf16(aH, bH, acc[g], 0,0,0);
          acc[g] = __builtin_amdgcn_mfma_f32_32x32x16_bf16(aH, bL, acc[g], 0,0,0);
          acc[g] = __builtin_amdgcn_mfma_f32_32x32x16_bf16(aL, bH, acc[g], 0,0,0);
        }
      }
      __syncthreads();
    }
    int col = colBase + hc*32 + lc;
    float bn = bhn1[col];
    #pragma unroll
    for (int r=0;r<16;++r){
      int row = rowBase + rf*32 + (r&3) + 8*(r>>2) + 4*lh;
      size_t gb = (size_t)row*H3 + col;
      float g_r = __builtin_nontemporal_load(&gi1[gb]);
      float g_z = __builtin_nontemporal_load(&gi1[gb + HH]);
      float g_n = __builtin_nontemporal_load(&gi1[gb + 2*HH]);
      float rg = sigm(g_r + acc[0][r]);
      float zg = sigm(g_z + acc[1][r]);
      float ng = tanhf(g_n + rg*(acc[2][r] + bn));
      float o  = (1.f - zg)*ng + zg*hval[r];
      size_t oo = (size_t)row*HH + col;
      unsigned short hi = f2bf(o);
      y1h[oo] = hi;
      y1l[oo] = f2bf(o - bf2f(hi));
    }
  }
}

// ---------------- logits + first-max argmax (fully unrolled) ----------------
__global__ __launch_bounds__(256) void k_logits(const float* __restrict__ ae2,
    const float* __restrict__ e, float* __restrict__ out_logits, int* __restrict__ argk, int t0)
{
  __shared__ float es[KK*SS];
  int tid = threadIdx.x;
  for (int i=0;i<4;++i) es[tid + i*256] = e[tid + i*256];
  __syncthreads();
  int g = blockIdx.x*256 + tid;
  int t = t0 + (g >> 10), j = g & 1023;
  const float* arow = &ae2[(size_t)g * SS];
  float a[SS];
  #pragma unroll
  for (int i=0;i<16;++i){ float4 v = ((const float4*)arow)[i]; a[4*i]=v.x; a[4*i+1]=v.y; a[4*i+2]=v.z; a[4*i+3]=v.w; }
  float lg[KK];
  float best = -INFINITY; int bk = 0;
  #pragma unroll
  for (int k=0;k<KK;++k){
    float s2 = 0.f;
    #pragma unroll
    for (int s=0;s<SS;++s) s2 += a[s]*es[k*SS+s];
    lg[k] = s2;
    if (s2 > best){ best = s2; bk = k; }
  }
  int n = j >> 7, b = j & 127;
  size_t ob = ((size_t)((t*BB + b)*NN + n)) * KK;
  #pragma unroll
  for (int k4=0;k4<4;++k4)
    *(float4*)&out_logits[ob + k4*4] = make_float4(lg[k4*4],lg[k4*4+1],lg[k4*4+2],lg[k4*4+3]);
  argk[(t*BB + b)*NN + n] = bk;   // (b,n)-major: matches reference's prob/q index quirk
}

// ---------------- q selection (bf16 y2 input) ----------------
__global__ __launch_bounds__(64) void k_qsel(const unsigned short* __restrict__ y2b,
    const float* __restrict__ w1, const float* __restrict__ b1,
    const int* __restrict__ argk, float* __restrict__ outq)
{
  __shared__ float yr[HH];
  __shared__ float part[64];
  int bj = blockIdx.x;
  int tid = threadIdx.x;
  {
    uint4 v = *(const uint4*)&y2b[(size_t)bj*HH + tid*8];
    const unsigned short* p = (const unsigned short*)&v;
    #pragma unroll
    for (int j=0;j<8;++j) yr[tid*8 + j] = bf2f(p[j]);
  }
  __syncthreads();
  int k = argk[bj];
  int a = tid & 15, q4 = tid >> 4;
  const float* wp = &w1[(size_t)k*HH*AA + a];
  float s = 0.f;
  int h0 = q4*128;
  #pragma unroll 8
  for (int h=h0; h<h0+128; ++h) s += yr[h]*wp[(size_t)h*AA];
  part[tid] = s;
  __syncthreads();
  if (q4 == 0){
    float v = part[a] + part[a+16] + part[a+32] + part[a+48] + b1[k*AA + a];
    outq[(size_t)bj*AA + a] = v;
  }
}

// ---------------- orchestration ----------------
extern "C" void kernel_launch(void* const* d_in, const int* in_sizes, int n_in,
                              void* d_out, int out_size, void* d_ws, size_t ws_size,
                              hipStream_t stream)
{
  (void)in_sizes; (void)n_in; (void)out_size;
  const float* h1     = (const float*)d_in[0];
  const float* h2     = (const float*)d_in[1];
  const float* obs    = (const float*)d_in[2];
  const unsigned char* done_raw = (const unsigned char*)d_in[3];
  const float* W_embed=(const float*)d_in[4];  const float* b_embed=(const float*)d_in[5];
  const float* Wi1    =(const float*)d_in[6];  const float* bi1    =(const float*)d_in[7];
  const float* Wh1    =(const float*)d_in[8];  const float* bhn1   =(const float*)d_in[9];
  const float* W_sub  =(const float*)d_in[10]; const float* b_sub  =(const float*)d_in[11];
  const float* W_e1   =(const float*)d_in[12]; const float* b_e1   =(const float*)d_in[13];
  const float* W_e2   =(const float*)d_in[14]; const float* b_e2   =(const float*)d_in[15];
  const float* W_pol  =(const float*)d_in[16]; const float* b_pol  =(const float*)d_in[17];
  const float* Wi2    =(const float*)d_in[18]; const float* bi2    =(const float*)d_in[19];
  const float* Wh2    =(const float*)d_in[20]; const float* bhn2   =(const float*)d_in[21];
  const float* W_w1   =(const float*)d_in[22]; const float* b_w1   =(const float*)d_in[23];
  const float* W_b1   =(const float*)d_in[24]; const float* b_b1   =(const float*)d_in[25];

  float* out    = (float*)d_out;
  float* outHT1 = out;
  float* outHT2 = out + (size_t)NB*HH;
  float* outQ   = out + 2ull*NB*HH;
  float* outLG  = outQ + (size_t)TT*NB*AA;
  float* outSE  = outLG + (size_t)TT*BB*NN*KK;

  // ---- adaptive chunk size (float units) ----
  const size_t fixed_f = (size_t)TT*NB + 1024
                       + (size_t)KK*HH*AA + 256 + (size_t)TT*NB + 64
                       + 2ull*NB*HH/2      /*hl1 pair*/
                       + (size_t)NB*HH/2   /*h2b0*/
                       + 2ull*DD*HH/2 * 2
                       + 4ull*H3*HH
                       + (size_t)HH*SS;
  const size_t per_t_f = (size_t)NB*(2*H3 + SS)               // gbuf1, gbuf2, ae2buf
                       + (size_t)NB*(HH/2 + DD + HH + HH/2);  // buf2bf, obs pair, y1 pair, y2b
  int CH = 64;
  while (CH > 1 && (fixed_f + per_t_f*(size_t)CH)*4 > ws_size) CH >>= 1;

  float* gbuf1  = (float*)d_ws;                        // gi1 chunk
  float* gbuf2  = gbuf1  + (size_t)CH*NB*H3;           // gi2 chunk
  float* ae2buf = gbuf2  + (size_t)CH*NB*H3;           // CH*NB*SS
  float* maskp  = ae2buf + (size_t)CH*NB*SS;
  float* ws_e   = maskp  + (size_t)TT*NB;
  float* ws_w1  = ws_e   + 1024;
  float* ws_b1  = ws_w1  + (size_t)KK*HH*AA;
  int*   ws_argk= (int*)(ws_b1 + 256);
  int*   ws_flag= (int*)(ws_argk + (size_t)TT*NB);
  unsigned short* buf2bf = (unsigned short*)(ws_flag + 64);   // CH*NB*HH (sp bf16)
  unsigned short* obs_h  = buf2bf + (size_t)CH*NB*HH;
  unsigned short* obs_l  = obs_h  + (size_t)CH*NB*DD;
  unsigned short* y1_h   = obs_l  + (size_t)CH*NB*DD;         // CH*NB*HH (y1 pair = h1 carry)
  unsigned short* y1_l   = y1_h   + (size_t)CH*NB*HH;
  unsigned short* y2b    = y1_l   + (size_t)CH*NB*HH;         // CH*NB*HH (y2 bf16 = h2 carry)
  unsigned short* hl1h   = y2b    + (size_t)CH*NB*HH;         // NB*HH chunk-carry pair
  unsigned short* hl1l   = hl1h   + (size_t)NB*HH;
  unsigned short* h2b0   = hl1l   + (size_t)NB*HH;            // initial h2 bf16
  unsigned short* wembt_h= h2b0   + (size_t)NB*HH;
  unsigned short* wembt_l= wembt_h+ (size_t)HH*DD;
  unsigned short* wpolt_h= wembt_l+ (size_t)HH*DD;
  unsigned short* wpolt_l= wpolt_h+ (size_t)HH*DD;
  unsigned short* wi1t_h = wpolt_l+ (size_t)HH*DD;
  unsigned short* wi1t_l = wi1t_h + (size_t)H3*HH;
  unsigned short* wi2t_h = wi1t_l + (size_t)H3*HH;
  unsigned short* wi2t_l = wi2t_h + (size_t)H3*HH;
  unsigned short* wh1t_h = wi2t_l + (size_t)H3*HH;
  unsigned short* wh1t_l = wh1t_h + (size_t)H3*HH;
  unsigned short* wh2t_h = wh1t_l + (size_t)H3*HH;
  unsigned short* wh2t_l = wh2t_h + (size_t)H3*HH;
  unsigned short* wsubt_h= wh2t_l + (size_t)H3*HH;
  unsigned short* wsubt_l= wsubt_h+ (size_t)SS*HH;

  hipFuncSetAttribute((const void*)gru_step_mix5,
                      hipFuncAttributeMaxDynamicSharedMemorySize, 81920);

  // phase 0
  k_detect<<<1,256,0,stream>>>(done_raw, ws_flag);
  k_mask<<<TT*NB/256,256,0,stream>>>(done_raw, ws_flag, maskp);
  k_e<<<1,256,0,stream>>>(W_e1,b_e1,W_e2,b_e2,ws_e);
  k_w1b1<<<128,256,0,stream>>>(ws_e,W_w1,b_w1,W_b1,b_b1,ws_w1,ws_b1);
  k_se<<<2048,256,0,stream>>>(ws_e,outSE);
  k_tsplit<<<dim3(16,4),256,0,stream>>>(W_embed, wembt_h, wembt_l, DD, HH);
  k_tsplit<<<dim3(16,4),256,0,stream>>>(W_pol,   wpolt_h, wpolt_l, DD, HH);
  k_tsplit<<<dim3(48,16),256,0,stream>>>(Wi1, wi1t_h, wi1t_l, HH, H3);
  k_tsplit<<<dim3(48,16),256,0,stream>>>(Wi2, wi2t_h, wi2t_l, HH, H3);
  k_tsplit<<<dim3(48,16),256,0,stream>>>(Wh1, wh1t_h, wh1t_l, HH, H3);
  k_tsplit<<<dim3(48,16),256,0,stream>>>(Wh2, wh2t_h, wh2t_l, HH, H3);
  k_tsplit<<<dim3(2,16),256,0,stream>>>(W_sub, wsubt_h, wsubt_l, HH, SS);
  k_split_cast<<<NB*HH/8/256,256,0,stream>>>(h1, hl1h, hl1l, NB*HH/8);   // GRU1 carry pair
  k_cast_bf16<<<NB*HH/8/256,256,0,stream>>>(h2, h2b0, NB*HH/8);          // GRU2 initial bf16

  dim3 thr(256);
  const int NCH = TT / CH;
  for (int c = 0; c < NCH; ++c){
    int t0 = c * CH;
    int M = CH*NB;
    const float* obs_c = obs + (size_t)t0*NB*DD;
    k_split_cast<<<(M*DD/8+255)/256,256,0,stream>>>(obs_c, obs_h, obs_l, M*DD/8);
    // embed1 writes ae pair into y1 slots; gi1 consumes immediately (stream-ordered; scan overwrites after)
    mfma_gemm<DD,1,128,1,2><<<dim3(HH/128, M/128),thr,0,stream>>>(
        obs_h, obs_l, wembt_h, wembt_l, b_embed, nullptr, y1_h, y1_l, HH);
    mfma_gemm<HH,1,128,0,0><<<dim3(H3/128, M/128),thr,0,stream>>>(
        y1_h, y1_l, wi1t_h, wi1t_l, bi1, gbuf1, nullptr, nullptr, H3);
    mfma_gemm<DD,0,128,1,1><<<dim3(HH/128, M/128),thr,0,stream>>>(
        obs_h, obs_h, wpolt_h, wpolt_h, b_pol, nullptr, buf2bf, nullptr, HH);
    mfma_gemm<HH,0,128,0,0><<<dim3(H3/128, M/128),thr,0,stream>>>(
        buf2bf, buf2bf, wi2t_h, wi2t_h, bi2, gbuf2, nullptr, nullptr, H3);
    // dual-GRU scan (double-buffered LDS, XCD-pinned, bf16 carries)
    for (int lt = 0; lt < CH; ++lt){
      const unsigned short* hp1h = (lt == 0) ? hl1h : (y1_h + (size_t)(lt-1)*NB*HH);
      const unsigned short* hp1l = (lt == 0) ? hl1l : (y1_l + (size_t)(lt-1)*NB*HH);
      const unsigned short* hp2b = (c == 0 && lt == 0) ? h2b0 :
                                   (lt == 0 ? y2b + (size_t)(CH-1)*NB*HH
                                            : y2b + (size_t)(lt-1)*NB*HH);
      gru_step_mix5<<<256, 256, 81920, stream>>>(hp1h, hp1l, hp2b,
                                                 gbuf1 + (size_t)lt*NB*H3, gbuf2 + (size_t)lt*NB*H3,
                                                 wh1t_h, wh1t_l, wh2t_h, bhn1, bhn2,
                                                 maskp + (size_t)(t0+lt)*NB,
                                                 y2b + (size_t)lt*NB*HH,
                                                 y1_h + (size_t)lt*NB*HH, y1_l + (size_t)lt*NB*HH);
    }
    // chunk carry for GRU1 (y1 slots are overwritten by next chunk's embed1)
    k_copy<<<256,256,0,stream>>>((const float*)(y1_h + (size_t)(CH-1)*NB*HH), (float*)hl1h, NB*HH/8);
    k_copy<<<256,256,0,stream>>>((const float*)(y1_l + (size_t)(CH-1)*NB*HH), (float*)hl1l, NB*HH/8);
    // tails
    mfma_gemm<HH,1,64,0,0><<<dim3(1, M/128),thr,0,stream>>>(
        y1_h, y1_l, wsubt_h, wsubt_l, b_sub, ae2buf, nullptr, nullptr, SS);
    k_logits<<<M/256,256,0,stream>>>(ae2buf, ws_e, outLG, ws_argk, t0);
    k_qsel<<<M,64,0,stream>>>(y2b, ws_w1, ws_b1, ws_argk + (size_t)t0*NB, outQ + (size_t)t0*NB*AA);
  }
  k_merge<<<NB*HH/8/256,256,0,stream>>>(hl1h, hl1l, outHT1, NB*HH/8);
  k_expand<<<NB*HH/8/256,256,0,stream>>>(y2b + (size_t)(CH-1)*NB*HH, outHT2, NB*HH/8);
}